// Round 12
// baseline (939.237 us; speedup 1.0000x reference)
//
#include <hip/hip_runtime.h>
#include <hip/hip_bf16.h>

#define T_   64
#define N_   50000
#define E_   1600000
#define GH_  32
#define RH_  64
#define TB32_ 32                   // timesteps per GRU pass (merged)
#define G32B_ 12500                // gather blocks: N / (4 waves/block)
#define GB_  782                   // gru blocks: cdiv(N,64)
#define NB_  196                   // node blocks: cdiv(N,256)
#define AB_  12500                 // aall blocks: N / (4 waves/block)

typedef _Float16 half_t;
typedef __attribute__((ext_vector_type(8))) _Float16 half8;
typedef __attribute__((ext_vector_type(4))) _Float16 half4;
typedef __attribute__((ext_vector_type(4))) float f32x4;
typedef __attribute__((ext_vector_type(4))) int i32x4;

static __device__ __forceinline__ float fast_sigmoid(float v) {
    float e = __expf(-v);
    return __builtin_amdgcn_rcpf(1.0f + e);
}
static __device__ __forceinline__ float fast_tanh(float v) {
    return 2.0f * fast_sigmoid(2.0f * v) - 1.0f;
}

// ---------- prologue ----------

// dyn [T,N] fp32 -> dynT [N,T] fp16
__global__ __launch_bounds__(256)
void k_transpose(const float* __restrict__ dyn, half_t* __restrict__ dynT) {
    __shared__ float tile[64][65];
    int n0 = blockIdx.x * 64;
    int tx = threadIdx.x, ty = threadIdx.y;
#pragma unroll
    for (int r = 0; r < 16; ++r) {
        int t = r * 4 + ty;
        int n = n0 + tx;
        tile[t][tx] = (n < N_) ? dyn[(size_t)t * N_ + n] : 0.0f;
    }
    __syncthreads();
#pragma unroll
    for (int r = 0; r < 16; ++r) {
        int nl = r * 4 + ty;
        int n = n0 + nl;
        if (n < N_) dynT[(size_t)n * 64 + tx] = (half_t)tile[tx][nl];
    }
}

// per-(dst, src-tile) histogram
__global__ void k_hist(const int* __restrict__ src, const int* __restrict__ dst,
                       int* __restrict__ cnt) {
    int e = blockIdx.x * blockDim.x + threadIdx.x;
    if (e >= E_) return;
    atomicAdd(&cnt[dst[e] * 16 + (src[e] >> 12)], 1);
}

// deg from cnt + per-block inclusive scan
__global__ __launch_bounds__(256)
void k_scanA(const int* __restrict__ cnt, int* __restrict__ deg,
             int* __restrict__ row_ptr, int* __restrict__ bsum) {
    __shared__ int buf[256];
    int tid = threadIdx.x;
    int i = blockIdx.x * 256 + tid;
    int v = 0;
    if (i < N_) {
        const int4* c4 = (const int4*)(cnt + i * 16);
#pragma unroll
        for (int c = 0; c < 4; ++c) {
            int4 w = c4[c];
            v += w.x + w.y + w.z + w.w;
        }
        deg[i] = v;
    }
    buf[tid] = v;
    __syncthreads();
#pragma unroll
    for (int off = 1; off < 256; off <<= 1) {
        int t = (tid >= off) ? buf[tid - off] : 0;
        __syncthreads();
        buf[tid] += t;
        __syncthreads();
    }
    if (i < N_) row_ptr[i + 1] = buf[tid];
    if (tid == 255) bsum[blockIdx.x] = buf[255];
}
__global__ __launch_bounds__(256)
void k_scanB(int* __restrict__ bsum, int nb) {
    __shared__ int buf[256];
    int tid = threadIdx.x;
    buf[tid] = (tid < nb) ? bsum[tid] : 0;
    __syncthreads();
#pragma unroll
    for (int off = 1; off < 256; off <<= 1) {
        int t = (tid >= off) ? buf[tid - off] : 0;
        __syncthreads();
        buf[tid] += t;
        __syncthreads();
    }
    if (tid < nb) bsum[tid] = (tid > 0) ? buf[tid - 1] : 0;
}
__global__ __launch_bounds__(256)
void k_scanC(int* __restrict__ row_ptr, const int* __restrict__ bsum) {
    int i = blockIdx.x * 256 + threadIdx.x;
    if (i == 0) row_ptr[0] = 0;
    if (i < N_) row_ptr[i + 1] += bsum[blockIdx.x];
}

// rp2[n][t] = row_ptr[n] + prefix(cnt[n][0..t)); zero cnt (reused as cursor)
__global__ __launch_bounds__(256)
void k_rowscan(const int* __restrict__ row_ptr, int* __restrict__ cnt,
               int* __restrict__ rp2) {
    int n = blockIdx.x * 256 + threadIdx.x;
    if (n >= N_) return;
    int run = row_ptr[n];
#pragma unroll
    for (int t = 0; t < 16; ++t) {
        int c = cnt[n * 16 + t];
        rp2[n * 16 + t] = run;
        run += c;
        cnt[n * 16 + t] = 0;
    }
}

__global__ __launch_bounds__(256)
void k_node_init(const int* __restrict__ deg,
                 const float* __restrict__ statics,
                 const float* __restrict__ w0,
                 float* __restrict__ dinv,
                 float* __restrict__ selfn,
                 half_t* __restrict__ h0s) {          // [N,32] f16
    int n = blockIdx.x * blockDim.x + threadIdx.x;
    if (n >= N_) return;
    float d  = (float)deg[n] + 1.0f;
    float di = rsqrtf(d);
    dinv[n] = di;
    selfn[n] = di * di;
    float s[6];
#pragma unroll
    for (int j = 0; j < 6; ++j) s[j] = statics[n * 6 + j];
    half8 o[4];
#pragma unroll
    for (int k = 0; k < GH_; ++k) {
        float v = 0.0f;
#pragma unroll
        for (int j = 0; j < 6; ++j) v += s[j] * w0[(1 + j) * GH_ + k];
        o[k >> 3][k & 7] = (half_t)v;
    }
    half8* dst8 = (half8*)(h0s + (size_t)n * GH_);
#pragma unroll
    for (int c = 0; c < 4; ++c) dst8[c] = o[c];
}

// tile-ordered scatter: 8-byte record {src, norm}
__global__ void k_scatter2(const int* __restrict__ src, const int* __restrict__ dst,
                           const float* __restrict__ dinv,
                           const int* __restrict__ rp2, int* __restrict__ cnt,
                           int2* __restrict__ erec) {
    int e = blockIdx.x * blockDim.x + threadIdx.x;
    if (e >= E_) return;
    int s = src[e], d = dst[e];
    int slot = d * 16 + (s >> 12);
    int pos = rp2[slot] + atomicAdd(&cnt[slot], 1);
    erec[pos] = make_int2(s, __float_as_int(dinv[s] * dinv[d]));
}

// pre-swizzled GRU weight fragments, f16.
__global__ void k_wB(const float* __restrict__ wih, const float* __restrict__ whh,
                     half_t* __restrict__ wB) {
    int idx = blockIdx.x * 256 + threadIdx.x;
    if (idx >= 96 * 192) return;
    int j = idx & 7;
    int r = idx >> 3;
    int m = r & 15; r >>= 4;
    int q = r & 3;  r >>= 2;
    int nt = r % 12;
    int c = r / 12;
    int k = c * 32 + q * 8 + j;
    int col = nt * 16 + m;
    float v = (k < 32) ? wih[col * 32 + k] : whh[col * 64 + (k - 32)];
    wB[idx] = (half_t)v;
}

// pre-swizzled w1 fragments, f16: w1B[((nt*4+q)*16+m)*8+j] = w1[k=q*8+j][col=nt*16+m]
__global__ void k_w1B(const float* __restrict__ w1, half_t* __restrict__ w1B) {
    int idx = blockIdx.x * 256 + threadIdx.x;
    if (idx >= 1024) return;
    int j = idx & 7;
    int m = (idx >> 3) & 15;
    int q = (idx >> 7) & 3;
    int nt = idx >> 9;
    w1B[idx] = (half_t)w1[(q * 8 + j) * GH_ + nt * 16 + m];
}

// ---------- fused aall + csagg gather (layer-1 aggregation) ----------

// aTh[n][t] f16 = agg of dyn (scalar per t).
static __device__ __forceinline__
void aall_body(int bid, const int* __restrict__ row_ptr, const int2* __restrict__ erec,
               const float* __restrict__ selfn, const half_t* __restrict__ dynT,
               half_t* __restrict__ aTh) {
    int wv = __builtin_amdgcn_readfirstlane(threadIdx.x >> 6);
    int n = bid * 4 + wv;                         // exact: AB_*4 == N_
    int lane = threadIdx.x & 63;
    float acc = selfn[n] * (float)dynT[(size_t)n * 64 + lane];
    int e0 = row_ptr[n], e1 = row_ptr[n + 1];     // wave-uniform (s_load)
    int e = e0;
    for (; e < e1 && (e & 3); ++e) {
        int2 r = erec[e];
        acc += __int_as_float(r.y) * (float)dynT[(size_t)r.x * 64 + lane];
    }
    for (; e + 4 <= e1; e += 4) {
        int4 p0 = *(const int4*)(erec + e);
        int4 p1 = *(const int4*)(erec + e + 2);
        float v0 = (float)dynT[(size_t)p0.x * 64 + lane];
        float v1 = (float)dynT[(size_t)p0.z * 64 + lane];
        float v2 = (float)dynT[(size_t)p1.x * 64 + lane];
        float v3 = (float)dynT[(size_t)p1.z * 64 + lane];
        acc += __int_as_float(p0.y) * v0 + __int_as_float(p0.w) * v1
             + __int_as_float(p1.y) * v2 + __int_as_float(p1.w) * v3;
    }
    for (; e < e1; ++e) {
        int2 r = erec[e];
        acc += __int_as_float(r.y) * (float)dynT[(size_t)r.x * 64 + lane];
    }
    aTh[(size_t)n * 64 + lane] = (half_t)acc;
}

// ch[n][32] f16 = agg of static-part (h0s) + b0 folded
static __device__ __forceinline__
void g16s_body(int bid, const int* __restrict__ row_ptr, const int2* __restrict__ erec,
               const float* __restrict__ selfn, const half_t* __restrict__ h0s,
               const float* __restrict__ b0, half_t* __restrict__ ch) {
    int gid = bid * 256 + threadIdx.x;
    int n = gid >> 2, q = gid & 3;
    if (n >= N_) return;
    const half8* f8 = (const half8*)h0s;
    float acc[8];
    {
        half8 sv = f8[(size_t)n * 4 + q];
        float sn = selfn[n];
#pragma unroll
        for (int i = 0; i < 8; ++i) acc[i] = sn * (float)sv[i];
    }
    int e0 = row_ptr[n], e1 = row_ptr[n + 1];
    int e = e0;
    for (; e < e1 && (e & 3); ++e) {
        int2 r = erec[e];
        float nm = __int_as_float(r.y);
        half8 v = f8[(size_t)r.x * 4 + q];
#pragma unroll
        for (int i = 0; i < 8; ++i) acc[i] += nm * (float)v[i];
    }
    for (; e + 4 <= e1; e += 4) {
        int4 p0 = *(const int4*)(erec + e);
        int4 p1 = *(const int4*)(erec + e + 2);
        half8 v0 = f8[(size_t)p0.x * 4 + q];
        half8 v1 = f8[(size_t)p0.z * 4 + q];
        half8 v2 = f8[(size_t)p1.x * 4 + q];
        half8 v3 = f8[(size_t)p1.z * 4 + q];
        float n0 = __int_as_float(p0.y), n1 = __int_as_float(p0.w);
        float n2 = __int_as_float(p1.y), n3 = __int_as_float(p1.w);
#pragma unroll
        for (int i = 0; i < 8; ++i)
            acc[i] += n0 * (float)v0[i] + n1 * (float)v1[i]
                    + n2 * (float)v2[i] + n3 * (float)v3[i];
    }
    for (; e < e1; ++e) {
        int2 r = erec[e];
        float nm = __int_as_float(r.y);
        half8 v = f8[(size_t)r.x * 4 + q];
#pragma unroll
        for (int i = 0; i < 8; ++i) acc[i] += nm * (float)v[i];
    }
    half8 o;
#pragma unroll
    for (int i = 0; i < 8; ++i) o[i] = (half_t)(acc[i] + b0[q * 8 + i]);
    *(half8*)(ch + (size_t)n * GH_ + q * 8) = o;
}

__global__ __launch_bounds__(256)
void k_aux(const int* __restrict__ row_ptr, const int2* __restrict__ erec,
           const float* __restrict__ selfn, const half_t* __restrict__ dynT,
           half_t* __restrict__ aTh, const half_t* __restrict__ h0s,
           const float* __restrict__ b0, half_t* __restrict__ ch) {
    if ((int)blockIdx.x < AB_)
        aall_body(blockIdx.x, row_ptr, erec, selfn, dynT, aTh);
    else
        g16s_body((int)blockIdx.x - AB_, row_ptr, erec, selfn, h0s, b0, ch);
}

// ---------- fused layer-2 gather + @w1 MFMA epilogue (ALL 64 t, one pass) ----
// One wave per node; wave-uniform edge loop (n via readfirstlane).
// Lane covers t = tg8..tg8+7 (ONE half8 a-load/edge) x k = kc..kc+3.
// The edge stream (erec/row_ptr/selfn/ch) is paid ONCE for all 64 t,
// vs twice in the 32-t variant. Math identical per element.
__global__ __launch_bounds__(256)
void k_gather64(const int* __restrict__ row_ptr, const int2* __restrict__ erec,
                const float* __restrict__ selfn,
                const half_t* __restrict__ aTh,   // [N][64] f16
                const half_t* __restrict__ ch,    // [N][32] f16 (b0 folded)
                const float* __restrict__ w0,     // row 0 used
                const half_t* __restrict__ w1B,   // swizzled w1 frags
                const float* __restrict__ b1,
                half_t* __restrict__ xblk) {      // [64][N][32] f16
    __shared__ half_t sh[4 * 64 * 40];            // 4 waves x 64 t x pad-40
    int tid = threadIdx.x;
    int wv = __builtin_amdgcn_readfirstlane(tid >> 6);
    int n = blockIdx.x * 4 + wv;                  // exact: G32B_*4 == N_
    int l = tid & 63;
    int tg8 = (l >> 3) * 8;                       // t base: 0,8,..,56
    int kc = (l & 7) * 4;                         // k chunk of 4
    float w0r[4];
#pragma unroll
    for (int i = 0; i < 4; ++i) w0r[i] = w0[kc + i];

    const half_t* aBase = aTh + tg8;              // + s*64 per src
    float acc[8][4];

    auto edge_acc = [&](half8 aa, half4 cc, float nmv) {
#pragma unroll
        for (int tt = 0; tt < 8; ++tt) {
#pragma unroll
            for (int i = 0; i < 4; ++i) {
                float hv = fmaxf(fmaf((float)aa[tt], w0r[i], (float)cc[i]), 0.0f);
                acc[tt][i] = fmaf(nmv, hv, acc[tt][i]);
            }
        }
    };

    {   // self-loop term
        float sn = selfn[n];
        half8 a8 = *(const half8*)(aBase + (size_t)n * 64);
        half4 c4 = *(const half4*)(ch + (size_t)n * GH_ + kc);
#pragma unroll
        for (int tt = 0; tt < 8; ++tt) {
#pragma unroll
            for (int i = 0; i < 4; ++i) {
                float hv = fmaxf(fmaf((float)a8[tt], w0r[i], (float)c4[i]), 0.0f);
                acc[tt][i] = sn * hv;
            }
        }
    }

    int e0 = row_ptr[n], e1 = row_ptr[n + 1];     // wave-uniform (s_load)
    int e = e0;
    if (e < e1 && (e & 1)) {                      // align to 16B erec pairs
        int2 r = erec[e];
        half8 a8 = *(const half8*)(aBase + (size_t)r.x * 64);
        half4 c4 = *(const half4*)(ch + (size_t)r.x * GH_ + kc);
        edge_acc(a8, c4, __int_as_float(r.y));
        ++e;
    }
    for (; e + 2 <= e1; e += 2) {
        i32x4 p0 = *(const i32x4*)(erec + e);
        size_t s0 = (size_t)p0[0], s1 = (size_t)p0[2];
        half8 a80 = *(const half8*)(aBase + s0 * 64);
        half8 a81 = *(const half8*)(aBase + s1 * 64);
        half4 c40 = *(const half4*)(ch + s0 * GH_ + kc);
        half4 c41 = *(const half4*)(ch + s1 * GH_ + kc);
        edge_acc(a80, c40, __int_as_float(p0[1]));
        edge_acc(a81, c41, __int_as_float(p0[3]));
    }
    for (; e < e1; ++e) {
        int2 r = erec[e];
        half8 a8 = *(const half8*)(aBase + (size_t)r.x * 64);
        half4 c4 = *(const half4*)(ch + (size_t)r.x * GH_ + kc);
        edge_acc(a8, c4, __int_as_float(r.y));
    }

    // acc -> per-wave LDS tile (f16); pad-40 rows keep half8 reads 16B-aligned.
    half_t* shw = sh + wv * 64 * 40;
#pragma unroll
    for (int tt = 0; tt < 8; ++tt) {
        half4 o;
#pragma unroll
        for (int i = 0; i < 4; ++i) o[i] = (half_t)acc[tt][i];
        *(half4*)(shw + (tg8 + tt) * 40 + kc) = o;
    }

    // epilogue operands (loaded after the edge loop)
    int c16 = l & 15, q = l >> 4;
    const half8* wB8 = (const half8*)w1B;
    half8 bf0 = wB8[(0 * 4 + q) * 16 + c16];
    half8 bf1 = wB8[(1 * 4 + q) * 16 + c16];
    float b1v0 = b1[c16], b1v1 = b1[16 + c16];

    const f32x4 zero = {0.0f, 0.0f, 0.0f, 0.0f};
    half8 A[4];
#pragma unroll
    for (int b = 0; b < 4; ++b)
        A[b] = *(const half8*)(shw + (b * 16 + c16) * 40 + q * 8);
    f32x4 C0[4], C1[4];
#pragma unroll
    for (int b = 0; b < 4; ++b) {
        C0[b] = __builtin_amdgcn_mfma_f32_16x16x32_f16(A[b], bf0, zero, 0, 0, 0);
        C1[b] = __builtin_amdgcn_mfma_f32_16x16x32_f16(A[b], bf1, zero, 0, 0, 0);
    }
    // writeback (A[] already in regs, safe to clobber rows)
#pragma unroll
    for (int b = 0; b < 4; ++b)
#pragma unroll
        for (int reg = 0; reg < 4; ++reg) {
            int row = b * 16 + q * 4 + reg;
            shw[row * 40 + c16]      = (half_t)fmaxf(C0[b][reg] + b1v0, 0.0f);
            shw[row * 40 + 16 + c16] = (half_t)fmaxf(C1[b][reg] + b1v1, 0.0f);
        }

    // coalesced store: 4 x half8/lane; 4 lanes cover one full 64B t-row
#pragma unroll
    for (int i = 0; i < 4; ++i) {
        int idx = i * 64 + l;
        int tl = idx >> 2;                        // 0..63
        int kcol = (idx & 3) * 8;
        half8 v = *(const half8*)(shw + tl * 40 + kcol);
        *(half8*)(xblk + ((size_t)tl * N_ + n) * GH_ + kcol) = v;
    }
}

// ---------- fallback: 32-t gather (round-10 exact) ----------
__global__ __launch_bounds__(256)
void k_gather32(const int* __restrict__ row_ptr, const int2* __restrict__ erec,
                const float* __restrict__ selfn,
                const half_t* __restrict__ aTh,   // [N][64] f16
                const half_t* __restrict__ ch,    // [N][32] f16 (b0 folded)
                const float* __restrict__ w0,     // row 0 used
                const half_t* __restrict__ w1B,   // swizzled w1 frags
                const float* __restrict__ b1,
                half_t* __restrict__ xblk,        // [32][N][32] f16
                int h) {
    __shared__ half_t sh[4 * 32 * 40];
    int tid = threadIdx.x;
    int wv = __builtin_amdgcn_readfirstlane(tid >> 6);
    int n = blockIdx.x * 4 + wv;
    int l = tid & 63;
    int tg4 = (l >> 3) * 4;
    int kc = (l & 7) * 4;
    float w0r[4];
#pragma unroll
    for (int i = 0; i < 4; ++i) w0r[i] = w0[kc + i];
    const half_t* aBase = aTh + h * 32 + tg4;
    float acc[4][4];

    auto edge_acc = [&](half4 aa, half4 cc, float nmv) {
#pragma unroll
        for (int tt = 0; tt < 4; ++tt)
#pragma unroll
            for (int i = 0; i < 4; ++i) {
                float hv = fmaxf(fmaf((float)aa[tt], w0r[i], (float)cc[i]), 0.0f);
                acc[tt][i] = fmaf(nmv, hv, acc[tt][i]);
            }
    };

    {
        float sn = selfn[n];
        half4 a4 = *(const half4*)(aBase + (size_t)n * 64);
        half4 c4 = *(const half4*)(ch + (size_t)n * GH_ + kc);
#pragma unroll
        for (int tt = 0; tt < 4; ++tt)
#pragma unroll
            for (int i = 0; i < 4; ++i) {
                float hv = fmaxf(fmaf((float)a4[tt], w0r[i], (float)c4[i]), 0.0f);
                acc[tt][i] = sn * hv;
            }
    }

    int e0 = row_ptr[n], e1 = row_ptr[n + 1];
    int e = e0;
    if (e < e1 && (e & 1)) {
        int2 r = erec[e];
        half4 a4 = *(const half4*)(aBase + (size_t)r.x * 64);
        half4 c4 = *(const half4*)(ch + (size_t)r.x * GH_ + kc);
        edge_acc(a4, c4, __int_as_float(r.y));
        ++e;
    }
    for (; e + 4 <= e1; e += 4) {
        i32x4 p0 = *(const i32x4*)(erec + e);
        i32x4 p1 = *(const i32x4*)(erec + e + 2);
        size_t s0 = (size_t)p0[0], s1 = (size_t)p0[2];
        size_t s2 = (size_t)p1[0], s3 = (size_t)p1[2];
        half4 a40 = *(const half4*)(aBase + s0 * 64);
        half4 a41 = *(const half4*)(aBase + s1 * 64);
        half4 a42 = *(const half4*)(aBase + s2 * 64);
        half4 a43 = *(const half4*)(aBase + s3 * 64);
        half4 c40 = *(const half4*)(ch + s0 * GH_ + kc);
        half4 c41 = *(const half4*)(ch + s1 * GH_ + kc);
        half4 c42 = *(const half4*)(ch + s2 * GH_ + kc);
        half4 c43 = *(const half4*)(ch + s3 * GH_ + kc);
        edge_acc(a40, c40, __int_as_float(p0[1]));
        edge_acc(a41, c41, __int_as_float(p0[3]));
        edge_acc(a42, c42, __int_as_float(p1[1]));
        edge_acc(a43, c43, __int_as_float(p1[3]));
    }
    for (; e < e1; ++e) {
        int2 r = erec[e];
        half4 a4 = *(const half4*)(aBase + (size_t)r.x * 64);
        half4 c4 = *(const half4*)(ch + (size_t)r.x * GH_ + kc);
        edge_acc(a4, c4, __int_as_float(r.y));
    }

    half_t* shw = sh + wv * 32 * 40;
#pragma unroll
    for (int tt = 0; tt < 4; ++tt) {
        half4 o;
#pragma unroll
        for (int i = 0; i < 4; ++i) o[i] = (half_t)acc[tt][i];
        *(half4*)(shw + (tg4 + tt) * 40 + kc) = o;
    }

    int c16 = l & 15, q = l >> 4;
    const half8* wB8 = (const half8*)w1B;
    half8 bf0 = wB8[(0 * 4 + q) * 16 + c16];
    half8 bf1 = wB8[(1 * 4 + q) * 16 + c16];
    float b1v0 = b1[c16], b1v1 = b1[16 + c16];

    const f32x4 zero = {0.0f, 0.0f, 0.0f, 0.0f};
    half8 A0 = *(const half8*)(shw + (0 * 16 + c16) * 40 + q * 8);
    half8 A1 = *(const half8*)(shw + (1 * 16 + c16) * 40 + q * 8);
    f32x4 C00 = __builtin_amdgcn_mfma_f32_16x16x32_f16(A0, bf0, zero, 0, 0, 0);
    f32x4 C01 = __builtin_amdgcn_mfma_f32_16x16x32_f16(A0, bf1, zero, 0, 0, 0);
    f32x4 C10 = __builtin_amdgcn_mfma_f32_16x16x32_f16(A1, bf0, zero, 0, 0, 0);
    f32x4 C11 = __builtin_amdgcn_mfma_f32_16x16x32_f16(A1, bf1, zero, 0, 0, 0);
#pragma unroll
    for (int reg = 0; reg < 4; ++reg) {
        shw[(q * 4 + reg) * 40 + c16]           = (half_t)fmaxf(C00[reg] + b1v0, 0.0f);
        shw[(q * 4 + reg) * 40 + 16 + c16]      = (half_t)fmaxf(C01[reg] + b1v1, 0.0f);
        shw[(16 + q * 4 + reg) * 40 + c16]      = (half_t)fmaxf(C10[reg] + b1v0, 0.0f);
        shw[(16 + q * 4 + reg) * 40 + 16 + c16] = (half_t)fmaxf(C11[reg] + b1v1, 0.0f);
    }
#pragma unroll
    for (int i = 0; i < 2; ++i) {
        int idx = i * 64 + l;
        int tl = idx >> 2;
        int kcol = (idx & 3) * 8;
        half8 v = *(const half8*)(shw + tl * 40 + kcol);
        *(half8*)(xblk + ((size_t)tl * N_ + n) * GH_ + kcol) = v;
    }
}

// ---------- MFMA GRU (one merged pass of 32 timesteps) ----------
#define HSTR_ 72
__global__ __launch_bounds__(256, 2)
void k_gru32(const half_t* __restrict__ xblk,  // [32][N][32] f16 (slice base)
             const half_t* __restrict__ wB,    // swizzled fragments
             const float* __restrict__ bih, const float* __restrict__ bhh,
             half_t* __restrict__ hA) {        // [Npad][64] f16
    __shared__ half_t hL[64 * HSTR_];
    int tid = threadIdx.x;
    int nb0 = blockIdx.x * 64;
    for (int i = tid; i < 64 * 8; i += 256) {
        int node = i >> 3, ch = i & 7;
        half8 v = *(const half8*)(hA + (size_t)(nb0 + node) * RH_ + ch * 8);
        *(half8*)(hL + node * HSTR_ + ch * 8) = v;
    }
    __syncthreads();
    int lane = tid & 63;
    int wv = tid >> 6;
    int c16 = lane & 15, q = lane >> 4;
    const half8* wB8 = (const half8*)wB;
    half8 bfr[3][12];
#pragma unroll
    for (int c = 0; c < 3; ++c)
#pragma unroll
        for (int nt = 0; nt < 12; ++nt)
            bfr[c][nt] = wB8[((c * 12 + nt) * 4 + q) * 16 + c16];
    float br[4], bz[4], bnx[4], bnh[4];
#pragma unroll
    for (int jt = 0; jt < 4; ++jt) {
        int j = jt * 16 + c16;
        br[jt]  = bih[j] + bhh[j];
        bz[jt]  = bih[64 + j] + bhh[64 + j];
        bnx[jt] = bih[128 + j];
        bnh[jt] = bhh[128 + j];
    }
    int mrow = wv * 16 + c16;
    const half_t* hrow = hL + mrow * HSTR_;
    half_t hreg[4][4];
#pragma unroll
    for (int jt = 0; jt < 4; ++jt)
#pragma unroll
        for (int reg = 0; reg < 4; ++reg)
            hreg[jt][reg] = hL[(wv * 16 + q * 4 + reg) * HSTR_ + jt * 16 + c16];
    const f32x4 zero = {0.0f, 0.0f, 0.0f, 0.0f};
#pragma unroll 1
    for (int u = 0; u < TB32_; ++u) {
        half8 ax = __builtin_nontemporal_load(
            (const half8*)(xblk + ((size_t)u * N_ + nb0 + mrow) * GH_ + q * 8));
        half8 ah0 = *(const half8*)(hrow + q * 8);
        half8 ah1 = *(const half8*)(hrow + 32 + q * 8);
        f32x4 Crz[8], Cnx[4], Cnh[4];
#pragma unroll
        for (int nt = 0; nt < 8; ++nt) {
            Crz[nt] = __builtin_amdgcn_mfma_f32_16x16x32_f16(ax,  bfr[0][nt], zero,     0, 0, 0);
            Crz[nt] = __builtin_amdgcn_mfma_f32_16x16x32_f16(ah0, bfr[1][nt], Crz[nt], 0, 0, 0);
            Crz[nt] = __builtin_amdgcn_mfma_f32_16x16x32_f16(ah1, bfr[2][nt], Crz[nt], 0, 0, 0);
        }
#pragma unroll
        for (int nt = 0; nt < 4; ++nt) {
            Cnx[nt] = __builtin_amdgcn_mfma_f32_16x16x32_f16(ax,  bfr[0][8 + nt], zero,     0, 0, 0);
            Cnh[nt] = __builtin_amdgcn_mfma_f32_16x16x32_f16(ah0, bfr[1][8 + nt], zero,     0, 0, 0);
            Cnh[nt] = __builtin_amdgcn_mfma_f32_16x16x32_f16(ah1, bfr[2][8 + nt], Cnh[nt], 0, 0, 0);
        }
#pragma unroll
        for (int jt = 0; jt < 4; ++jt) {
#pragma unroll
            for (int reg = 0; reg < 4; ++reg) {
                int nl = wv * 16 + q * 4 + reg;
                int jj = jt * 16 + c16;
                float hold = (float)hreg[jt][reg];
                float r  = fast_sigmoid(Crz[jt][reg] + br[jt]);
                float z  = fast_sigmoid(Crz[4 + jt][reg] + bz[jt]);
                float cd = fast_tanh(Cnx[jt][reg] + bnx[jt] + r * (Cnh[jt][reg] + bnh[jt]));
                half_t hnew = (half_t)((1.0f - z) * cd + z * hold);
                hreg[jt][reg] = hnew;
                hL[nl * HSTR_ + jj] = hnew;
            }
        }
    }
    __syncthreads();
    for (int i = tid; i < 64 * 8; i += 256) {
        int node = i >> 3, ch = i & 7;
        half8 v = *(const half8*)(hL + node * HSTR_ + ch * 8);
        *(half8*)(hA + (size_t)(nb0 + node) * RH_ + ch * 8) = v;
    }
}

__global__ __launch_bounds__(256)
void k_mlp(const half_t* __restrict__ hA, const float* __restrict__ w1,
           const float* __restrict__ b1, const float* __restrict__ w2,
           const float* __restrict__ b2, float* __restrict__ out) {
    int n = blockIdx.x * blockDim.x + threadIdx.x;
    if (n >= N_) return;
    float h[RH_];
    const half8* h8 = (const half8*)(hA + (size_t)n * RH_);
#pragma unroll
    for (int c = 0; c < 8; ++c) {
        half8 v = h8[c];
#pragma unroll
        for (int i = 0; i < 8; ++i) h[c * 8 + i] = (float)v[i];
    }
    float acc = b2[0];
#pragma unroll 1
    for (int j = 0; j < RH_; ++j) {
        float v = b1[j];
#pragma unroll
        for (int k = 0; k < RH_; ++k) v += w1[j * RH_ + k] * h[k];
        v = v > 0.0f ? v : 0.0f;
        acc += w2[j] * v;
    }
    out[n] = acc;
}

extern "C" void kernel_launch(void* const* d_in, const int* in_sizes, int n_in,
                              void* d_out, int out_size, void* d_ws, size_t ws_size,
                              hipStream_t stream) {
    const float* dyn     = (const float*)d_in[0];
    const float* statics = (const float*)d_in[1];
    const int*   ei      = (const int*)d_in[2];
    const float* w0      = (const float*)d_in[3];
    const float* b0      = (const float*)d_in[4];
    const float* w1      = (const float*)d_in[5];
    const float* b1      = (const float*)d_in[6];
    const float* wih     = (const float*)d_in[7];
    const float* whh     = (const float*)d_in[8];
    const float* bih     = (const float*)d_in[9];
    const float* bhh     = (const float*)d_in[10];
    const float* mw1     = (const float*)d_in[11];
    const float* mb1     = (const float*)d_in[12];
    const float* mw2     = (const float*)d_in[13];
    const float* mb2     = (const float*)d_in[14];
    const int* src = ei;
    const int* dst = ei + E_;

    char* ws = (char*)d_ws;
    auto alloc = [&](size_t elems) {        // 4B units, 256B-aligned
        elems = (elems + 63) & ~(size_t)63;
        void* p = ws; ws += elems * 4; return p;
    };
    const int NPAD = N_ + 64;
    int*    deg     = (int*)alloc(N_);
    int*    row_ptr = (int*)alloc(N_ + 4);
    int*    bsum    = (int*)alloc(256);
    int*    cnt     = (int*)alloc((size_t)N_ * 16);
    int*    rp2     = (int*)alloc((size_t)N_ * 16);
    int2*   erec    = (int2*)alloc((size_t)E_ * 2);
    float*  dinv    = (float*)alloc(N_);
    float*  selfn   = (float*)alloc(N_);
    half_t* h0s     = (half_t*)alloc((size_t)N_ * GH_ / 2);        // f16 [N,32]
    half_t* ch      = (half_t*)alloc((size_t)N_ * GH_ / 2);        // f16 [N,32]
    half_t* aTh     = (half_t*)alloc((size_t)N_ * 64 / 2);         // f16 [N,64]
    half_t* hA      = (half_t*)alloc((size_t)NPAD * RH_ / 2);      // f16 [Npad][64]
    half_t* dynT    = (half_t*)alloc((size_t)N_ * 64 / 2);         // f16 [N][64]
    half_t* wB      = (half_t*)alloc(96 * 192 / 2);
    half_t* w1B     = (half_t*)alloc(1024 / 2);
    // xblk last: [64][N][32] if workspace permits, else [32][N][32] (fallback)
    size_t used = (size_t)(ws - (char*)d_ws);
    size_t xblk64_bytes = ((size_t)64 * N_ + 64) * GH_ * sizeof(half_t);
    bool use64 = (ws_size >= used + xblk64_bytes + 4096);
    half_t* xblk = (half_t*)ws;

    auto cdiv = [](long long x, int b) { return (unsigned)((x + b - 1) / b); };
    const int B = 256;

    hipMemsetAsync(cnt, 0, (size_t)N_ * 16 * sizeof(int), stream);
    hipMemsetAsync(hA, 0, (size_t)NPAD * RH_ * sizeof(half_t), stream);

    k_transpose<<<cdiv(N_, 64), dim3(64, 4), 0, stream>>>(dyn, dynT);
    k_hist<<<cdiv(E_, B), B, 0, stream>>>(src, dst, cnt);
    k_scanA<<<NB_, B, 0, stream>>>(cnt, deg, row_ptr, bsum);
    k_scanB<<<1, B, 0, stream>>>(bsum, NB_);
    k_scanC<<<NB_, B, 0, stream>>>(row_ptr, bsum);
    k_rowscan<<<NB_, B, 0, stream>>>(row_ptr, cnt, rp2);
    k_node_init<<<NB_, B, 0, stream>>>(deg, statics, w0, dinv, selfn, h0s);
    k_scatter2<<<cdiv(E_, B), B, 0, stream>>>(src, dst, dinv, rp2, cnt, erec);
    k_wB<<<cdiv(96 * 192, B), B, 0, stream>>>(wih, whh, wB);
    k_w1B<<<4, B, 0, stream>>>(w1, w1B);
    k_aux<<<AB_ + GB_, B, 0, stream>>>(row_ptr, erec, selfn, dynT, aTh, h0s, b0, ch);

    if (use64) {
        k_gather64<<<G32B_, B, 0, stream>>>(row_ptr, erec, selfn, aTh, ch, w0,
                                            w1B, b1, xblk);
        k_gru32<<<GB_, B, 0, stream>>>(xblk, wB, bih, bhh, hA);
        k_gru32<<<GB_, B, 0, stream>>>(xblk + (size_t)32 * N_ * GH_, wB, bih, bhh, hA);
    } else {
        for (int h = 0; h < 2; ++h) {
            k_gather32<<<G32B_, B, 0, stream>>>(row_ptr, erec, selfn, aTh, ch, w0,
                                                w1B, b1, xblk, h);
            k_gru32<<<GB_, B, 0, stream>>>(xblk, wB, bih, bhh, hA);
        }
    }
    k_mlp<<<NB_, B, 0, stream>>>(hA, mw1, mb1, mw2, mb2, (float*)d_out);
}

// Round 13
// 916.327 us; speedup vs baseline: 1.0250x; 1.0250x over previous
//
#include <hip/hip_runtime.h>
#include <hip/hip_bf16.h>

#define T_   64
#define N_   50000
#define E_   1600000
#define GH_  32
#define RH_  64
#define TB32_ 32                   // timesteps per GRU pass (merged)
#define GB_  782                   // gru blocks: cdiv(N,64)
#define NB_  196                   // node blocks: cdiv(N,256)
#define AB_  12500                 // aall blocks: N / (4 waves/block)

typedef _Float16 half_t;
typedef __attribute__((ext_vector_type(8))) _Float16 half8;
typedef __attribute__((ext_vector_type(4))) _Float16 half4;
typedef __attribute__((ext_vector_type(4))) float f32x4;
typedef __attribute__((ext_vector_type(4))) int i32x4;

static __device__ __forceinline__ float fast_sigmoid(float v) {
    float e = __expf(-v);
    return __builtin_amdgcn_rcpf(1.0f + e);
}
static __device__ __forceinline__ float fast_tanh(float v) {
    return 2.0f * fast_sigmoid(2.0f * v) - 1.0f;
}

// ---------- prologue ----------

// dyn [T,N] fp32 -> dynT [N,T] fp16
__global__ __launch_bounds__(256)
void k_transpose(const float* __restrict__ dyn, half_t* __restrict__ dynT) {
    __shared__ float tile[64][65];
    int n0 = blockIdx.x * 64;
    int tx = threadIdx.x, ty = threadIdx.y;
#pragma unroll
    for (int r = 0; r < 16; ++r) {
        int t = r * 4 + ty;
        int n = n0 + tx;
        tile[t][tx] = (n < N_) ? dyn[(size_t)t * N_ + n] : 0.0f;
    }
    __syncthreads();
#pragma unroll
    for (int r = 0; r < 16; ++r) {
        int nl = r * 4 + ty;
        int n = n0 + nl;
        if (n < N_) dynT[(size_t)n * 64 + tx] = (half_t)tile[tx][nl];
    }
}

// per-(dst, src-tile) histogram
__global__ void k_hist(const int* __restrict__ src, const int* __restrict__ dst,
                       int* __restrict__ cnt) {
    int e = blockIdx.x * blockDim.x + threadIdx.x;
    if (e >= E_) return;
    atomicAdd(&cnt[dst[e] * 16 + (src[e] >> 12)], 1);
}

// deg from cnt + per-block inclusive scan
__global__ __launch_bounds__(256)
void k_scanA(const int* __restrict__ cnt, int* __restrict__ deg,
             int* __restrict__ row_ptr, int* __restrict__ bsum) {
    __shared__ int buf[256];
    int tid = threadIdx.x;
    int i = blockIdx.x * 256 + tid;
    int v = 0;
    if (i < N_) {
        const int4* c4 = (const int4*)(cnt + i * 16);
#pragma unroll
        for (int c = 0; c < 4; ++c) {
            int4 w = c4[c];
            v += w.x + w.y + w.z + w.w;
        }
        deg[i] = v;
    }
    buf[tid] = v;
    __syncthreads();
#pragma unroll
    for (int off = 1; off < 256; off <<= 1) {
        int t = (tid >= off) ? buf[tid - off] : 0;
        __syncthreads();
        buf[tid] += t;
        __syncthreads();
    }
    if (i < N_) row_ptr[i + 1] = buf[tid];
    if (tid == 255) bsum[blockIdx.x] = buf[255];
}
__global__ __launch_bounds__(256)
void k_scanB(int* __restrict__ bsum, int nb) {
    __shared__ int buf[256];
    int tid = threadIdx.x;
    buf[tid] = (tid < nb) ? bsum[tid] : 0;
    __syncthreads();
#pragma unroll
    for (int off = 1; off < 256; off <<= 1) {
        int t = (tid >= off) ? buf[tid - off] : 0;
        __syncthreads();
        buf[tid] += t;
        __syncthreads();
    }
    if (tid < nb) bsum[tid] = (tid > 0) ? buf[tid - 1] : 0;
}
__global__ __launch_bounds__(256)
void k_scanC(int* __restrict__ row_ptr, const int* __restrict__ bsum) {
    int i = blockIdx.x * 256 + threadIdx.x;
    if (i == 0) row_ptr[0] = 0;
    if (i < N_) row_ptr[i + 1] += bsum[blockIdx.x];
}

// rp2[n][t] = row_ptr[n] + prefix(cnt[n][0..t)); zero cnt (reused as cursor)
__global__ __launch_bounds__(256)
void k_rowscan(const int* __restrict__ row_ptr, int* __restrict__ cnt,
               int* __restrict__ rp2) {
    int n = blockIdx.x * 256 + threadIdx.x;
    if (n >= N_) return;
    int run = row_ptr[n];
#pragma unroll
    for (int t = 0; t < 16; ++t) {
        int c = cnt[n * 16 + t];
        rp2[n * 16 + t] = run;
        run += c;
        cnt[n * 16 + t] = 0;
    }
}

__global__ __launch_bounds__(256)
void k_node_init(const int* __restrict__ deg,
                 const float* __restrict__ statics,
                 const float* __restrict__ w0,
                 float* __restrict__ dinv,
                 float* __restrict__ selfn,
                 half_t* __restrict__ h0s) {          // [N,32] f16
    int n = blockIdx.x * blockDim.x + threadIdx.x;
    if (n >= N_) return;
    float d  = (float)deg[n] + 1.0f;
    float di = rsqrtf(d);
    dinv[n] = di;
    selfn[n] = di * di;
    float s[6];
#pragma unroll
    for (int j = 0; j < 6; ++j) s[j] = statics[n * 6 + j];
    half8 o[4];
#pragma unroll
    for (int k = 0; k < GH_; ++k) {
        float v = 0.0f;
#pragma unroll
        for (int j = 0; j < 6; ++j) v += s[j] * w0[(1 + j) * GH_ + k];
        o[k >> 3][k & 7] = (half_t)v;
    }
    half8* dst8 = (half8*)(h0s + (size_t)n * GH_);
#pragma unroll
    for (int c = 0; c < 4; ++c) dst8[c] = o[c];
}

// tile-ordered scatter: 8-byte record {src, norm}
__global__ void k_scatter2(const int* __restrict__ src, const int* __restrict__ dst,
                           const float* __restrict__ dinv,
                           const int* __restrict__ rp2, int* __restrict__ cnt,
                           int2* __restrict__ erec) {
    int e = blockIdx.x * blockDim.x + threadIdx.x;
    if (e >= E_) return;
    int s = src[e], d = dst[e];
    int slot = d * 16 + (s >> 12);
    int pos = rp2[slot] + atomicAdd(&cnt[slot], 1);
    erec[pos] = make_int2(s, __float_as_int(dinv[s] * dinv[d]));
}

// pre-swizzled GRU weight fragments, f16.
__global__ void k_wB(const float* __restrict__ wih, const float* __restrict__ whh,
                     half_t* __restrict__ wB) {
    int idx = blockIdx.x * 256 + threadIdx.x;
    if (idx >= 96 * 192) return;
    int j = idx & 7;
    int r = idx >> 3;
    int m = r & 15; r >>= 4;
    int q = r & 3;  r >>= 2;
    int nt = r % 12;
    int c = r / 12;
    int k = c * 32 + q * 8 + j;
    int col = nt * 16 + m;
    float v = (k < 32) ? wih[col * 32 + k] : whh[col * 64 + (k - 32)];
    wB[idx] = (half_t)v;
}

// pre-swizzled w1 fragments, f16: w1B[((nt*4+q)*16+m)*8+j] = w1[k=q*8+j][col=nt*16+m]
__global__ void k_w1B(const float* __restrict__ w1, half_t* __restrict__ w1B) {
    int idx = blockIdx.x * 256 + threadIdx.x;
    if (idx >= 1024) return;
    int j = idx & 7;
    int m = (idx >> 3) & 15;
    int q = (idx >> 7) & 3;
    int nt = idx >> 9;
    w1B[idx] = (half_t)w1[(q * 8 + j) * GH_ + nt * 16 + m];
}

// ---------- fused aall + csagg gather (layer-1 aggregation) ----------

// aTh[n][t] f16 = agg of dyn (scalar per t).
static __device__ __forceinline__
void aall_body(int bid, const int* __restrict__ row_ptr, const int2* __restrict__ erec,
               const float* __restrict__ selfn, const half_t* __restrict__ dynT,
               half_t* __restrict__ aTh) {
    int wv = __builtin_amdgcn_readfirstlane(threadIdx.x >> 6);
    int n = bid * 4 + wv;                         // exact: AB_*4 == N_
    int lane = threadIdx.x & 63;
    float acc = selfn[n] * (float)dynT[(size_t)n * 64 + lane];
    int e0 = row_ptr[n], e1 = row_ptr[n + 1];     // wave-uniform (s_load)
    int e = e0;
    for (; e < e1 && (e & 3); ++e) {
        int2 r = erec[e];
        acc += __int_as_float(r.y) * (float)dynT[(size_t)r.x * 64 + lane];
    }
    for (; e + 4 <= e1; e += 4) {
        int4 p0 = *(const int4*)(erec + e);
        int4 p1 = *(const int4*)(erec + e + 2);
        float v0 = (float)dynT[(size_t)p0.x * 64 + lane];
        float v1 = (float)dynT[(size_t)p0.z * 64 + lane];
        float v2 = (float)dynT[(size_t)p1.x * 64 + lane];
        float v3 = (float)dynT[(size_t)p1.z * 64 + lane];
        acc += __int_as_float(p0.y) * v0 + __int_as_float(p0.w) * v1
             + __int_as_float(p1.y) * v2 + __int_as_float(p1.w) * v3;
    }
    for (; e < e1; ++e) {
        int2 r = erec[e];
        acc += __int_as_float(r.y) * (float)dynT[(size_t)r.x * 64 + lane];
    }
    aTh[(size_t)n * 64 + lane] = (half_t)acc;
}

// ch[n][32] f16 = agg of static-part (h0s) + b0 folded
static __device__ __forceinline__
void g16s_body(int bid, const int* __restrict__ row_ptr, const int2* __restrict__ erec,
               const float* __restrict__ selfn, const half_t* __restrict__ h0s,
               const float* __restrict__ b0, half_t* __restrict__ ch) {
    int gid = bid * 256 + threadIdx.x;
    int n = gid >> 2, q = gid & 3;
    if (n >= N_) return;
    const half8* f8 = (const half8*)h0s;
    float acc[8];
    {
        half8 sv = f8[(size_t)n * 4 + q];
        float sn = selfn[n];
#pragma unroll
        for (int i = 0; i < 8; ++i) acc[i] = sn * (float)sv[i];
    }
    int e0 = row_ptr[n], e1 = row_ptr[n + 1];
    int e = e0;
    for (; e < e1 && (e & 3); ++e) {
        int2 r = erec[e];
        float nm = __int_as_float(r.y);
        half8 v = f8[(size_t)r.x * 4 + q];
#pragma unroll
        for (int i = 0; i < 8; ++i) acc[i] += nm * (float)v[i];
    }
    for (; e + 4 <= e1; e += 4) {
        int4 p0 = *(const int4*)(erec + e);
        int4 p1 = *(const int4*)(erec + e + 2);
        half8 v0 = f8[(size_t)p0.x * 4 + q];
        half8 v1 = f8[(size_t)p0.z * 4 + q];
        half8 v2 = f8[(size_t)p1.x * 4 + q];
        half8 v3 = f8[(size_t)p1.z * 4 + q];
        float n0 = __int_as_float(p0.y), n1 = __int_as_float(p0.w);
        float n2 = __int_as_float(p1.y), n3 = __int_as_float(p1.w);
#pragma unroll
        for (int i = 0; i < 8; ++i)
            acc[i] += n0 * (float)v0[i] + n1 * (float)v1[i]
                    + n2 * (float)v2[i] + n3 * (float)v3[i];
    }
    for (; e < e1; ++e) {
        int2 r = erec[e];
        float nm = __int_as_float(r.y);
        half8 v = f8[(size_t)r.x * 4 + q];
#pragma unroll
        for (int i = 0; i < 8; ++i) acc[i] += nm * (float)v[i];
    }
    half8 o;
#pragma unroll
    for (int i = 0; i < 8; ++i) o[i] = (half_t)(acc[i] + b0[q * 8 + i]);
    *(half8*)(ch + (size_t)n * GH_ + q * 8) = o;
}

__global__ __launch_bounds__(256)
void k_aux(const int* __restrict__ row_ptr, const int2* __restrict__ erec,
           const float* __restrict__ selfn, const half_t* __restrict__ dynT,
           half_t* __restrict__ aTh, const half_t* __restrict__ h0s,
           const float* __restrict__ b0, half_t* __restrict__ ch) {
    if ((int)blockIdx.x < AB_)
        aall_body(blockIdx.x, row_ptr, erec, selfn, dynT, aTh);
    else
        g16s_body((int)blockIdx.x - AB_, row_ptr, erec, selfn, h0s, b0, ch);
}

// ---------- fused layer-2 gather + @w1 MFMA epilogue ----------
// ONE WAVE PER BLOCK (64 threads, grid = N): n = blockIdx.x is SGPR by
// construction; wave retirement is decoupled from sibling-wave stragglers
// (degree variance), and dispatch drain is finer-grained.
// Per edge: reconstruct h1 = relu(a*w0+c); converts fold into v_fma_mix.
// Epilogue: acc -> LDS (32x40 f16) -> MFMA @w1 -> (+b1, relu, f16) back to
// LDS -> 2x half8 coalesced stores/lane.
// Lane map (edge loop): tg = l>>3 covers t_loc tg*4..+4, kc = (l&7)*4.
__global__ __launch_bounds__(64)
void k_gather32(const int* __restrict__ row_ptr, const int2* __restrict__ erec,
                const float* __restrict__ selfn,
                const half_t* __restrict__ aTh,   // [N][64] f16
                const half_t* __restrict__ ch,    // [N][32] f16 (b0 folded)
                const float* __restrict__ w0,     // row 0 used
                const half_t* __restrict__ w1B,   // swizzled w1 frags
                const float* __restrict__ b1,
                half_t* __restrict__ xblk,        // [32][N][32] f16
                int h) {
    __shared__ half_t shw[32 * 40];               // one wave x 32 t x pad-40
    int n = blockIdx.x;                           // grid = N_, SGPR-uniform
    int l = threadIdx.x;                          // 0..63
    int tg4 = (l >> 3) * 4;                       // t-group base
    int kc = (l & 7) * 4;                         // k chunk of 4
    float w0r[4];
#pragma unroll
    for (int i = 0; i < 4; ++i) w0r[i] = w0[kc + i];

    const half_t* aBase = aTh + h * 32 + tg4;     // + s*64 per src
    float acc[4][4];

    auto edge_acc = [&](half4 aa, half4 cc, float nmv) {
#pragma unroll
        for (int tt = 0; tt < 4; ++tt) {
#pragma unroll
            for (int i = 0; i < 4; ++i) {
                // fmaf(fpext(f16), f32, fpext(f16)) -> v_fma_mix_f32
                float hv = fmaxf(fmaf((float)aa[tt], w0r[i], (float)cc[i]), 0.0f);
                acc[tt][i] = fmaf(nmv, hv, acc[tt][i]);
            }
        }
    };

    {   // self-loop term
        float sn = selfn[n];
        half4 a4 = *(const half4*)(aBase + (size_t)n * 64);
        half4 c4 = *(const half4*)(ch + (size_t)n * GH_ + kc);
#pragma unroll
        for (int tt = 0; tt < 4; ++tt) {
#pragma unroll
            for (int i = 0; i < 4; ++i) {
                float hv = fmaxf(fmaf((float)a4[tt], w0r[i], (float)c4[i]), 0.0f);
                acc[tt][i] = sn * hv;
            }
        }
    }

    int e0 = row_ptr[n], e1 = row_ptr[n + 1];     // wave-uniform (s_load)
    int e = e0;
    if (e < e1 && (e & 1)) {                      // align to 16B erec pairs
        int2 r = erec[e];
        half4 a4 = *(const half4*)(aBase + (size_t)r.x * 64);
        half4 c4 = *(const half4*)(ch + (size_t)r.x * GH_ + kc);
        edge_acc(a4, c4, __int_as_float(r.y));
        ++e;
    }
    for (; e + 4 <= e1; e += 4) {
        i32x4 p0 = *(const i32x4*)(erec + e);
        i32x4 p1 = *(const i32x4*)(erec + e + 2);
        size_t s0 = (size_t)p0[0], s1 = (size_t)p0[2];
        size_t s2 = (size_t)p1[0], s3 = (size_t)p1[2];
        half4 a40 = *(const half4*)(aBase + s0 * 64);
        half4 a41 = *(const half4*)(aBase + s1 * 64);
        half4 a42 = *(const half4*)(aBase + s2 * 64);
        half4 a43 = *(const half4*)(aBase + s3 * 64);
        half4 c40 = *(const half4*)(ch + s0 * GH_ + kc);
        half4 c41 = *(const half4*)(ch + s1 * GH_ + kc);
        half4 c42 = *(const half4*)(ch + s2 * GH_ + kc);
        half4 c43 = *(const half4*)(ch + s3 * GH_ + kc);
        edge_acc(a40, c40, __int_as_float(p0[1]));
        edge_acc(a41, c41, __int_as_float(p0[3]));
        edge_acc(a42, c42, __int_as_float(p1[1]));
        edge_acc(a43, c43, __int_as_float(p1[3]));
    }
    for (; e < e1; ++e) {
        int2 r = erec[e];
        half4 a4 = *(const half4*)(aBase + (size_t)r.x * 64);
        half4 c4 = *(const half4*)(ch + (size_t)r.x * GH_ + kc);
        edge_acc(a4, c4, __int_as_float(r.y));
    }

    // acc -> wave-private LDS tile (f16); pad-40 rows keep half8 reads aligned.
    // Single wave: ds_write -> ds_read ordered via lgkmcnt, no barrier.
#pragma unroll
    for (int tt = 0; tt < 4; ++tt) {
        half4 o;
#pragma unroll
        for (int i = 0; i < 4; ++i) o[i] = (half_t)acc[tt][i];
        *(half4*)(shw + (tg4 + tt) * 40 + kc) = o;
    }

    // epilogue operands (loaded now: keeps them out of the loop's live range)
    int c16 = l & 15, q = l >> 4;
    const half8* wB8 = (const half8*)w1B;
    half8 bf0 = wB8[(0 * 4 + q) * 16 + c16];
    half8 bf1 = wB8[(1 * 4 + q) * 16 + c16];
    float b1v0 = b1[c16], b1v1 = b1[16 + c16];

    const f32x4 zero = {0.0f, 0.0f, 0.0f, 0.0f};
    half8 A0 = *(const half8*)(shw + (0 * 16 + c16) * 40 + q * 8);
    half8 A1 = *(const half8*)(shw + (1 * 16 + c16) * 40 + q * 8);
    f32x4 C00 = __builtin_amdgcn_mfma_f32_16x16x32_f16(A0, bf0, zero, 0, 0, 0);
    f32x4 C01 = __builtin_amdgcn_mfma_f32_16x16x32_f16(A0, bf1, zero, 0, 0, 0);
    f32x4 C10 = __builtin_amdgcn_mfma_f32_16x16x32_f16(A1, bf0, zero, 0, 0, 0);
    f32x4 C11 = __builtin_amdgcn_mfma_f32_16x16x32_f16(A1, bf1, zero, 0, 0, 0);

    // C writeback into the same tile (A0/A1 already in regs, safe to clobber)
#pragma unroll
    for (int reg = 0; reg < 4; ++reg) {
        shw[(q * 4 + reg) * 40 + c16]           = (half_t)fmaxf(C00[reg] + b1v0, 0.0f);
        shw[(q * 4 + reg) * 40 + 16 + c16]      = (half_t)fmaxf(C01[reg] + b1v1, 0.0f);
        shw[(16 + q * 4 + reg) * 40 + c16]      = (half_t)fmaxf(C10[reg] + b1v0, 0.0f);
        shw[(16 + q * 4 + reg) * 40 + 16 + c16] = (half_t)fmaxf(C11[reg] + b1v1, 0.0f);
    }

    // coalesced store: 2 x half8/lane; 4 lanes cover one full 64B t-row
#pragma unroll
    for (int i = 0; i < 2; ++i) {
        int idx = i * 64 + l;
        int tl = idx >> 2;                        // 0..31
        int kcol = (idx & 3) * 8;
        half8 v = *(const half8*)(shw + tl * 40 + kcol);
        *(half8*)(xblk + ((size_t)tl * N_ + n) * GH_ + kcol) = v;
    }
}

// ---------- MFMA GRU (one merged pass of 32 timesteps) ----------
#define HSTR_ 72
__global__ __launch_bounds__(256, 2)
void k_gru32(const half_t* __restrict__ xblk,  // [32][N][32] f16 (slice base)
             const half_t* __restrict__ wB,    // swizzled fragments
             const float* __restrict__ bih, const float* __restrict__ bhh,
             half_t* __restrict__ hA) {        // [Npad][64] f16
    __shared__ half_t hL[64 * HSTR_];
    int tid = threadIdx.x;
    int nb0 = blockIdx.x * 64;
    for (int i = tid; i < 64 * 8; i += 256) {
        int node = i >> 3, ch = i & 7;
        half8 v = *(const half8*)(hA + (size_t)(nb0 + node) * RH_ + ch * 8);
        *(half8*)(hL + node * HSTR_ + ch * 8) = v;
    }
    __syncthreads();
    int lane = tid & 63;
    int wv = tid >> 6;
    int c16 = lane & 15, q = lane >> 4;
    const half8* wB8 = (const half8*)wB;
    half8 bfr[3][12];
#pragma unroll
    for (int c = 0; c < 3; ++c)
#pragma unroll
        for (int nt = 0; nt < 12; ++nt)
            bfr[c][nt] = wB8[((c * 12 + nt) * 4 + q) * 16 + c16];
    float br[4], bz[4], bnx[4], bnh[4];
#pragma unroll
    for (int jt = 0; jt < 4; ++jt) {
        int j = jt * 16 + c16;
        br[jt]  = bih[j] + bhh[j];
        bz[jt]  = bih[64 + j] + bhh[64 + j];
        bnx[jt] = bih[128 + j];
        bnh[jt] = bhh[128 + j];
    }
    int mrow = wv * 16 + c16;
    const half_t* hrow = hL + mrow * HSTR_;
    const f32x4 zero = {0.0f, 0.0f, 0.0f, 0.0f};
#pragma unroll 1
    for (int u = 0; u < TB32_; ++u) {
        half8 ax = __builtin_nontemporal_load(
            (const half8*)(xblk + ((size_t)u * N_ + nb0 + mrow) * GH_ + q * 8));
        half8 ah0 = *(const half8*)(hrow + q * 8);
        half8 ah1 = *(const half8*)(hrow + 32 + q * 8);
        f32x4 Crz[8], Cnx[4], Cnh[4];
#pragma unroll
        for (int nt = 0; nt < 8; ++nt) {
            Crz[nt] = __builtin_amdgcn_mfma_f32_16x16x32_f16(ax,  bfr[0][nt], zero,     0, 0, 0);
            Crz[nt] = __builtin_amdgcn_mfma_f32_16x16x32_f16(ah0, bfr[1][nt], Crz[nt], 0, 0, 0);
            Crz[nt] = __builtin_amdgcn_mfma_f32_16x16x32_f16(ah1, bfr[2][nt], Crz[nt], 0, 0, 0);
        }
#pragma unroll
        for (int nt = 0; nt < 4; ++nt) {
            Cnx[nt] = __builtin_amdgcn_mfma_f32_16x16x32_f16(ax,  bfr[0][8 + nt], zero,     0, 0, 0);
            Cnh[nt] = __builtin_amdgcn_mfma_f32_16x16x32_f16(ah0, bfr[1][8 + nt], zero,     0, 0, 0);
            Cnh[nt] = __builtin_amdgcn_mfma_f32_16x16x32_f16(ah1, bfr[2][8 + nt], Cnh[nt], 0, 0, 0);
        }
#pragma unroll
        for (int jt = 0; jt < 4; ++jt) {
#pragma unroll
            for (int reg = 0; reg < 4; ++reg) {
                int nl = wv * 16 + q * 4 + reg;
                int jj = jt * 16 + c16;
                float hold = (float)hL[nl * HSTR_ + jj];
                float r  = fast_sigmoid(Crz[jt][reg] + br[jt]);
                float z  = fast_sigmoid(Crz[4 + jt][reg] + bz[jt]);
                float cd = fast_tanh(Cnx[jt][reg] + bnx[jt] + r * (Cnh[jt][reg] + bnh[jt]));
                hL[nl * HSTR_ + jj] = (half_t)((1.0f - z) * cd + z * hold);
            }
        }
    }
    __syncthreads();
    for (int i = tid; i < 64 * 8; i += 256) {
        int node = i >> 3, ch = i & 7;
        half8 v = *(const half8*)(hL + node * HSTR_ + ch * 8);
        *(half8*)(hA + (size_t)(nb0 + node) * RH_ + ch * 8) = v;
    }
}

__global__ __launch_bounds__(256)
void k_mlp(const half_t* __restrict__ hA, const float* __restrict__ w1,
           const float* __restrict__ b1, const float* __restrict__ w2,
           const float* __restrict__ b2, float* __restrict__ out) {
    int n = blockIdx.x * blockDim.x + threadIdx.x;
    if (n >= N_) return;
    float h[RH_];
    const half8* h8 = (const half8*)(hA + (size_t)n * RH_);
#pragma unroll
    for (int c = 0; c < 8; ++c) {
        half8 v = h8[c];
#pragma unroll
        for (int i = 0; i < 8; ++i) h[c * 8 + i] = (float)v[i];
    }
    float acc = b2[0];
#pragma unroll 1
    for (int j = 0; j < RH_; ++j) {
        float v = b1[j];
#pragma unroll
        for (int k = 0; k < RH_; ++k) v += w1[j * RH_ + k] * h[k];
        v = v > 0.0f ? v : 0.0f;
        acc += w2[j] * v;
    }
    out[n] = acc;
}

extern "C" void kernel_launch(void* const* d_in, const int* in_sizes, int n_in,
                              void* d_out, int out_size, void* d_ws, size_t ws_size,
                              hipStream_t stream) {
    const float* dyn     = (const float*)d_in[0];
    const float* statics = (const float*)d_in[1];
    const int*   ei      = (const int*)d_in[2];
    const float* w0      = (const float*)d_in[3];
    const float* b0      = (const float*)d_in[4];
    const float* w1      = (const float*)d_in[5];
    const float* b1      = (const float*)d_in[6];
    const float* wih     = (const float*)d_in[7];
    const float* whh     = (const float*)d_in[8];
    const float* bih     = (const float*)d_in[9];
    const float* bhh     = (const float*)d_in[10];
    const float* mw1     = (const float*)d_in[11];
    const float* mb1     = (const float*)d_in[12];
    const float* mw2     = (const float*)d_in[13];
    const float* mb2     = (const float*)d_in[14];
    const int* src = ei;
    const int* dst = ei + E_;

    char* ws = (char*)d_ws;
    auto alloc = [&](size_t elems) {        // 4B units, 256B-aligned
        elems = (elems + 63) & ~(size_t)63;
        void* p = ws; ws += elems * 4; return p;
    };
    const int NPAD = N_ + 64;
    int*    deg     = (int*)alloc(N_);
    int*    row_ptr = (int*)alloc(N_ + 4);
    int*    bsum    = (int*)alloc(256);
    int*    cnt     = (int*)alloc((size_t)N_ * 16);
    int*    rp2     = (int*)alloc((size_t)N_ * 16);
    int2*   erec    = (int2*)alloc((size_t)E_ * 2);
    float*  dinv    = (float*)alloc(N_);
    float*  selfn   = (float*)alloc(N_);
    half_t* h0s     = (half_t*)alloc((size_t)N_ * GH_ / 2);        // f16 [N,32]
    half_t* ch      = (half_t*)alloc((size_t)N_ * GH_ / 2);        // f16 [N,32]
    half_t* aTh     = (half_t*)alloc((size_t)N_ * 64 / 2);         // f16 [N,64]
    half_t* xblk    = (half_t*)alloc(((size_t)32 * N_ + 64) * GH_ / 2); // f16 [32][N][32]
    half_t* hA      = (half_t*)alloc((size_t)NPAD * RH_ / 2);      // f16 [Npad][64]
    half_t* dynT    = (half_t*)alloc((size_t)N_ * 64 / 2);         // f16 [N][64]
    half_t* wB      = (half_t*)alloc(96 * 192 / 2);
    half_t* w1B     = (half_t*)alloc(1024 / 2);

    auto cdiv = [](long long x, int b) { return (unsigned)((x + b - 1) / b); };
    const int B = 256;

    hipMemsetAsync(cnt, 0, (size_t)N_ * 16 * sizeof(int), stream);
    hipMemsetAsync(hA, 0, (size_t)NPAD * RH_ * sizeof(half_t), stream);

    k_transpose<<<cdiv(N_, 64), dim3(64, 4), 0, stream>>>(dyn, dynT);
    k_hist<<<cdiv(E_, B), B, 0, stream>>>(src, dst, cnt);
    k_scanA<<<NB_, B, 0, stream>>>(cnt, deg, row_ptr, bsum);
    k_scanB<<<1, B, 0, stream>>>(bsum, NB_);
    k_scanC<<<NB_, B, 0, stream>>>(row_ptr, bsum);
    k_rowscan<<<NB_, B, 0, stream>>>(row_ptr, cnt, rp2);
    k_node_init<<<NB_, B, 0, stream>>>(deg, statics, w0, dinv, selfn, h0s);
    k_scatter2<<<cdiv(E_, B), B, 0, stream>>>(src, dst, dinv, rp2, cnt, erec);
    k_wB<<<cdiv(96 * 192, B), B, 0, stream>>>(wih, whh, wB);
    k_w1B<<<4, B, 0, stream>>>(w1, w1B);
    k_aux<<<AB_ + GB_, B, 0, stream>>>(row_ptr, erec, selfn, dynT, aTh, h0s, b0, ch);

    for (int h = 0; h < 2; ++h) {
        k_gather32<<<N_, 64, 0, stream>>>(row_ptr, erec, selfn, aTh, ch, w0,
                                          w1B, b1, xblk, h);
        k_gru32<<<GB_, B, 0, stream>>>(xblk, wB, bih, bhh, hA);
    }
    k_mlp<<<NB_, B, 0, stream>>>(hA, mw1, mb1, mw2, mb2, (float*)d_out);
}

// Round 14
// 914.633 us; speedup vs baseline: 1.0269x; 1.0019x over previous
//
#include <hip/hip_runtime.h>
#include <hip/hip_bf16.h>

#define T_   64
#define N_   50000
#define E_   1600000
#define GH_  32
#define RH_  64
#define TB32_ 32                   // timesteps per GRU pass (merged)
#define GB_  782                   // gru blocks: cdiv(N,64)
#define NB_  196                   // node blocks: cdiv(N,256)
#define AB_  12500                 // aall blocks: N / (4 waves/block)

typedef _Float16 half_t;
typedef __attribute__((ext_vector_type(8))) _Float16 half8;
typedef __attribute__((ext_vector_type(4))) _Float16 half4;
typedef __attribute__((ext_vector_type(4))) float f32x4;
typedef __attribute__((ext_vector_type(4))) int i32x4;

static __device__ __forceinline__ float fast_sigmoid(float v) {
    float e = __expf(-v);
    return __builtin_amdgcn_rcpf(1.0f + e);
}
static __device__ __forceinline__ float fast_tanh(float v) {
    return 2.0f * fast_sigmoid(2.0f * v) - 1.0f;
}

// ---------- prologue ----------

// dyn [T,N] fp32 -> dynT [N,T] fp16
__global__ __launch_bounds__(256)
void k_transpose(const float* __restrict__ dyn, half_t* __restrict__ dynT) {
    __shared__ float tile[64][65];
    int n0 = blockIdx.x * 64;
    int tx = threadIdx.x, ty = threadIdx.y;
#pragma unroll
    for (int r = 0; r < 16; ++r) {
        int t = r * 4 + ty;
        int n = n0 + tx;
        tile[t][tx] = (n < N_) ? dyn[(size_t)t * N_ + n] : 0.0f;
    }
    __syncthreads();
#pragma unroll
    for (int r = 0; r < 16; ++r) {
        int nl = r * 4 + ty;
        int n = n0 + nl;
        if (n < N_) dynT[(size_t)n * 64 + tx] = (half_t)tile[tx][nl];
    }
}

// per-(dst, src-tile) histogram
__global__ void k_hist(const int* __restrict__ src, const int* __restrict__ dst,
                       int* __restrict__ cnt) {
    int e = blockIdx.x * blockDim.x + threadIdx.x;
    if (e >= E_) return;
    atomicAdd(&cnt[dst[e] * 16 + (src[e] >> 12)], 1);
}

// deg from cnt + per-block inclusive scan
__global__ __launch_bounds__(256)
void k_scanA(const int* __restrict__ cnt, int* __restrict__ deg,
             int* __restrict__ row_ptr, int* __restrict__ bsum) {
    __shared__ int buf[256];
    int tid = threadIdx.x;
    int i = blockIdx.x * 256 + tid;
    int v = 0;
    if (i < N_) {
        const int4* c4 = (const int4*)(cnt + i * 16);
#pragma unroll
        for (int c = 0; c < 4; ++c) {
            int4 w = c4[c];
            v += w.x + w.y + w.z + w.w;
        }
        deg[i] = v;
    }
    buf[tid] = v;
    __syncthreads();
#pragma unroll
    for (int off = 1; off < 256; off <<= 1) {
        int t = (tid >= off) ? buf[tid - off] : 0;
        __syncthreads();
        buf[tid] += t;
        __syncthreads();
    }
    if (i < N_) row_ptr[i + 1] = buf[tid];
    if (tid == 255) bsum[blockIdx.x] = buf[255];
}
__global__ __launch_bounds__(256)
void k_scanB(int* __restrict__ bsum, int nb) {
    __shared__ int buf[256];
    int tid = threadIdx.x;
    buf[tid] = (tid < nb) ? bsum[tid] : 0;
    __syncthreads();
#pragma unroll
    for (int off = 1; off < 256; off <<= 1) {
        int t = (tid >= off) ? buf[tid - off] : 0;
        __syncthreads();
        buf[tid] += t;
        __syncthreads();
    }
    if (tid < nb) bsum[tid] = (tid > 0) ? buf[tid - 1] : 0;
}
__global__ __launch_bounds__(256)
void k_scanC(int* __restrict__ row_ptr, const int* __restrict__ bsum) {
    int i = blockIdx.x * 256 + threadIdx.x;
    if (i == 0) row_ptr[0] = 0;
    if (i < N_) row_ptr[i + 1] += bsum[blockIdx.x];
}

// rp2[n][t] = row_ptr[n] + prefix(cnt[n][0..t)); zero cnt (reused as cursor)
__global__ __launch_bounds__(256)
void k_rowscan(const int* __restrict__ row_ptr, int* __restrict__ cnt,
               int* __restrict__ rp2) {
    int n = blockIdx.x * 256 + threadIdx.x;
    if (n >= N_) return;
    int run = row_ptr[n];
#pragma unroll
    for (int t = 0; t < 16; ++t) {
        int c = cnt[n * 16 + t];
        rp2[n * 16 + t] = run;
        run += c;
        cnt[n * 16 + t] = 0;
    }
}

__global__ __launch_bounds__(256)
void k_node_init(const int* __restrict__ deg,
                 const float* __restrict__ statics,
                 const float* __restrict__ w0,
                 float* __restrict__ dinv,
                 float* __restrict__ selfn,
                 half_t* __restrict__ h0s) {          // [N,32] f16
    int n = blockIdx.x * blockDim.x + threadIdx.x;
    if (n >= N_) return;
    float d  = (float)deg[n] + 1.0f;
    float di = rsqrtf(d);
    dinv[n] = di;
    selfn[n] = di * di;
    float s[6];
#pragma unroll
    for (int j = 0; j < 6; ++j) s[j] = statics[n * 6 + j];
    half8 o[4];
#pragma unroll
    for (int k = 0; k < GH_; ++k) {
        float v = 0.0f;
#pragma unroll
        for (int j = 0; j < 6; ++j) v += s[j] * w0[(1 + j) * GH_ + k];
        o[k >> 3][k & 7] = (half_t)v;
    }
    half8* dst8 = (half8*)(h0s + (size_t)n * GH_);
#pragma unroll
    for (int c = 0; c < 4; ++c) dst8[c] = o[c];
}

// tile-ordered scatter: 8-byte record {src, norm}
__global__ void k_scatter2(const int* __restrict__ src, const int* __restrict__ dst,
                           const float* __restrict__ dinv,
                           const int* __restrict__ rp2, int* __restrict__ cnt,
                           int2* __restrict__ erec) {
    int e = blockIdx.x * blockDim.x + threadIdx.x;
    if (e >= E_) return;
    int s = src[e], d = dst[e];
    int slot = d * 16 + (s >> 12);
    int pos = rp2[slot] + atomicAdd(&cnt[slot], 1);
    erec[pos] = make_int2(s, __float_as_int(dinv[s] * dinv[d]));
}

// pre-swizzled GRU weight fragments, f16.
__global__ void k_wB(const float* __restrict__ wih, const float* __restrict__ whh,
                     half_t* __restrict__ wB) {
    int idx = blockIdx.x * 256 + threadIdx.x;
    if (idx >= 96 * 192) return;
    int j = idx & 7;
    int r = idx >> 3;
    int m = r & 15; r >>= 4;
    int q = r & 3;  r >>= 2;
    int nt = r % 12;
    int c = r / 12;
    int k = c * 32 + q * 8 + j;
    int col = nt * 16 + m;
    float v = (k < 32) ? wih[col * 32 + k] : whh[col * 64 + (k - 32)];
    wB[idx] = (half_t)v;
}

// pre-swizzled w1 fragments, f16: w1B[((nt*4+q)*16+m)*8+j] = w1[k=q*8+j][col=nt*16+m]
__global__ void k_w1B(const float* __restrict__ w1, half_t* __restrict__ w1B) {
    int idx = blockIdx.x * 256 + threadIdx.x;
    if (idx >= 1024) return;
    int j = idx & 7;
    int m = (idx >> 3) & 15;
    int q = (idx >> 7) & 3;
    int nt = idx >> 9;
    w1B[idx] = (half_t)w1[(q * 8 + j) * GH_ + nt * 16 + m];
}

// ---------- fused aall + csagg gather (layer-1 aggregation) ----------

// aTh[n][t] f16 = agg of dyn (scalar per t).
static __device__ __forceinline__
void aall_body(int bid, const int* __restrict__ row_ptr, const int2* __restrict__ erec,
               const float* __restrict__ selfn, const half_t* __restrict__ dynT,
               half_t* __restrict__ aTh) {
    int wv = __builtin_amdgcn_readfirstlane(threadIdx.x >> 6);
    int n = bid * 4 + wv;                         // exact: AB_*4 == N_
    int lane = threadIdx.x & 63;
    float acc = selfn[n] * (float)dynT[(size_t)n * 64 + lane];
    int e0 = row_ptr[n], e1 = row_ptr[n + 1];     // wave-uniform (s_load)
    int e = e0;
    for (; e < e1 && (e & 3); ++e) {
        int2 r = erec[e];
        acc += __int_as_float(r.y) * (float)dynT[(size_t)r.x * 64 + lane];
    }
    for (; e + 4 <= e1; e += 4) {
        int4 p0 = *(const int4*)(erec + e);
        int4 p1 = *(const int4*)(erec + e + 2);
        float v0 = (float)dynT[(size_t)p0.x * 64 + lane];
        float v1 = (float)dynT[(size_t)p0.z * 64 + lane];
        float v2 = (float)dynT[(size_t)p1.x * 64 + lane];
        float v3 = (float)dynT[(size_t)p1.z * 64 + lane];
        acc += __int_as_float(p0.y) * v0 + __int_as_float(p0.w) * v1
             + __int_as_float(p1.y) * v2 + __int_as_float(p1.w) * v3;
    }
    for (; e < e1; ++e) {
        int2 r = erec[e];
        acc += __int_as_float(r.y) * (float)dynT[(size_t)r.x * 64 + lane];
    }
    aTh[(size_t)n * 64 + lane] = (half_t)acc;
}

// ch[n][32] f16 = agg of static-part (h0s) + b0 folded
static __device__ __forceinline__
void g16s_body(int bid, const int* __restrict__ row_ptr, const int2* __restrict__ erec,
               const float* __restrict__ selfn, const half_t* __restrict__ h0s,
               const float* __restrict__ b0, half_t* __restrict__ ch) {
    int gid = bid * 256 + threadIdx.x;
    int n = gid >> 2, q = gid & 3;
    if (n >= N_) return;
    const half8* f8 = (const half8*)h0s;
    float acc[8];
    {
        half8 sv = f8[(size_t)n * 4 + q];
        float sn = selfn[n];
#pragma unroll
        for (int i = 0; i < 8; ++i) acc[i] = sn * (float)sv[i];
    }
    int e0 = row_ptr[n], e1 = row_ptr[n + 1];
    int e = e0;
    for (; e < e1 && (e & 3); ++e) {
        int2 r = erec[e];
        float nm = __int_as_float(r.y);
        half8 v = f8[(size_t)r.x * 4 + q];
#pragma unroll
        for (int i = 0; i < 8; ++i) acc[i] += nm * (float)v[i];
    }
    for (; e + 4 <= e1; e += 4) {
        int4 p0 = *(const int4*)(erec + e);
        int4 p1 = *(const int4*)(erec + e + 2);
        half8 v0 = f8[(size_t)p0.x * 4 + q];
        half8 v1 = f8[(size_t)p0.z * 4 + q];
        half8 v2 = f8[(size_t)p1.x * 4 + q];
        half8 v3 = f8[(size_t)p1.z * 4 + q];
        float n0 = __int_as_float(p0.y), n1 = __int_as_float(p0.w);
        float n2 = __int_as_float(p1.y), n3 = __int_as_float(p1.w);
#pragma unroll
        for (int i = 0; i < 8; ++i)
            acc[i] += n0 * (float)v0[i] + n1 * (float)v1[i]
                    + n2 * (float)v2[i] + n3 * (float)v3[i];
    }
    for (; e < e1; ++e) {
        int2 r = erec[e];
        float nm = __int_as_float(r.y);
        half8 v = f8[(size_t)r.x * 4 + q];
#pragma unroll
        for (int i = 0; i < 8; ++i) acc[i] += nm * (float)v[i];
    }
    half8 o;
#pragma unroll
    for (int i = 0; i < 8; ++i) o[i] = (half_t)(acc[i] + b0[q * 8 + i]);
    *(half8*)(ch + (size_t)n * GH_ + q * 8) = o;
}

__global__ __launch_bounds__(256)
void k_aux(const int* __restrict__ row_ptr, const int2* __restrict__ erec,
           const float* __restrict__ selfn, const half_t* __restrict__ dynT,
           half_t* __restrict__ aTh, const half_t* __restrict__ h0s,
           const float* __restrict__ b0, half_t* __restrict__ ch) {
    if ((int)blockIdx.x < AB_)
        aall_body(blockIdx.x, row_ptr, erec, selfn, dynT, aTh);
    else
        g16s_body((int)blockIdx.x - AB_, row_ptr, erec, selfn, h0s, b0, ch);
}

// ---------- fused layer-2 gather + @w1 MFMA epilogue (ALL 64 t, one pass) ----
// ONE WAVE PER BLOCK (r13-proven: decouples wave retirement from degree
// stragglers; n = blockIdx.x is SGPR by construction). Merged t-range
// (r12-proven correct): edge stream paid ONCE for all 64 timesteps.
// Lane covers t = tg8..tg8+7 (one half8 a-load/edge) x k = kc..kc+3.
__global__ __launch_bounds__(64)
void k_gather64(const int* __restrict__ row_ptr, const int2* __restrict__ erec,
                const float* __restrict__ selfn,
                const half_t* __restrict__ aTh,   // [N][64] f16
                const half_t* __restrict__ ch,    // [N][32] f16 (b0 folded)
                const float* __restrict__ w0,     // row 0 used
                const half_t* __restrict__ w1B,   // swizzled w1 frags
                const float* __restrict__ b1,
                half_t* __restrict__ xblk) {      // [64][N][32] f16
    __shared__ half_t shw[64 * 40];               // one wave x 64 t x pad-40
    int n = blockIdx.x;                           // grid = N_, SGPR-uniform
    int l = threadIdx.x;                          // 0..63
    int tg8 = (l >> 3) * 8;                       // t base: 0,8,..,56
    int kc = (l & 7) * 4;                         // k chunk of 4
    float w0r[4];
#pragma unroll
    for (int i = 0; i < 4; ++i) w0r[i] = w0[kc + i];

    const half_t* aBase = aTh + tg8;              // + s*64 per src
    float acc[8][4];

    auto edge_acc = [&](half8 aa, half4 cc, float nmv) {
#pragma unroll
        for (int tt = 0; tt < 8; ++tt) {
#pragma unroll
            for (int i = 0; i < 4; ++i) {
                // fmaf(fpext(f16), f32, fpext(f16)) -> v_fma_mix_f32
                float hv = fmaxf(fmaf((float)aa[tt], w0r[i], (float)cc[i]), 0.0f);
                acc[tt][i] = fmaf(nmv, hv, acc[tt][i]);
            }
        }
    };

    {   // self-loop term
        float sn = selfn[n];
        half8 a8 = *(const half8*)(aBase + (size_t)n * 64);
        half4 c4 = *(const half4*)(ch + (size_t)n * GH_ + kc);
#pragma unroll
        for (int tt = 0; tt < 8; ++tt) {
#pragma unroll
            for (int i = 0; i < 4; ++i) {
                float hv = fmaxf(fmaf((float)a8[tt], w0r[i], (float)c4[i]), 0.0f);
                acc[tt][i] = sn * hv;
            }
        }
    }

    int e0 = row_ptr[n], e1 = row_ptr[n + 1];     // wave-uniform (s_load)
    int e = e0;
    if (e < e1 && (e & 1)) {                      // align to 16B erec pairs
        int2 r = erec[e];
        half8 a8 = *(const half8*)(aBase + (size_t)r.x * 64);
        half4 c4 = *(const half4*)(ch + (size_t)r.x * GH_ + kc);
        edge_acc(a8, c4, __int_as_float(r.y));
        ++e;
    }
    for (; e + 2 <= e1; e += 2) {
        i32x4 p0 = *(const i32x4*)(erec + e);
        size_t s0 = (size_t)p0[0], s1 = (size_t)p0[2];
        half8 a80 = *(const half8*)(aBase + s0 * 64);
        half8 a81 = *(const half8*)(aBase + s1 * 64);
        half4 c40 = *(const half4*)(ch + s0 * GH_ + kc);
        half4 c41 = *(const half4*)(ch + s1 * GH_ + kc);
        edge_acc(a80, c40, __int_as_float(p0[1]));
        edge_acc(a81, c41, __int_as_float(p0[3]));
    }
    for (; e < e1; ++e) {
        int2 r = erec[e];
        half8 a8 = *(const half8*)(aBase + (size_t)r.x * 64);
        half4 c4 = *(const half4*)(ch + (size_t)r.x * GH_ + kc);
        edge_acc(a8, c4, __int_as_float(r.y));
    }

    // acc -> wave-private LDS tile (f16); pad-40 rows keep half8 reads aligned.
    // Single wave: ds_write -> ds_read ordered via lgkmcnt, no barrier.
#pragma unroll
    for (int tt = 0; tt < 8; ++tt) {
        half4 o;
#pragma unroll
        for (int i = 0; i < 4; ++i) o[i] = (half_t)acc[tt][i];
        *(half4*)(shw + (tg8 + tt) * 40 + kc) = o;
    }

    // epilogue operands (loaded after the edge loop)
    int c16 = l & 15, q = l >> 4;
    const half8* wB8 = (const half8*)w1B;
    half8 bf0 = wB8[(0 * 4 + q) * 16 + c16];
    half8 bf1 = wB8[(1 * 4 + q) * 16 + c16];
    float b1v0 = b1[c16], b1v1 = b1[16 + c16];

    const f32x4 zero = {0.0f, 0.0f, 0.0f, 0.0f};
    half8 A[4];
#pragma unroll
    for (int b = 0; b < 4; ++b)
        A[b] = *(const half8*)(shw + (b * 16 + c16) * 40 + q * 8);
    f32x4 C0[4], C1[4];
#pragma unroll
    for (int b = 0; b < 4; ++b) {
        C0[b] = __builtin_amdgcn_mfma_f32_16x16x32_f16(A[b], bf0, zero, 0, 0, 0);
        C1[b] = __builtin_amdgcn_mfma_f32_16x16x32_f16(A[b], bf1, zero, 0, 0, 0);
    }
    // writeback (A[] already in regs, safe to clobber rows)
#pragma unroll
    for (int b = 0; b < 4; ++b)
#pragma unroll
        for (int reg = 0; reg < 4; ++reg) {
            int row = b * 16 + q * 4 + reg;
            shw[row * 40 + c16]      = (half_t)fmaxf(C0[b][reg] + b1v0, 0.0f);
            shw[row * 40 + 16 + c16] = (half_t)fmaxf(C1[b][reg] + b1v1, 0.0f);
        }

    // coalesced store: 4 x half8/lane; 4 lanes cover one full 64B t-row
#pragma unroll
    for (int i = 0; i < 4; ++i) {
        int idx = i * 64 + l;
        int tl = idx >> 2;                        // 0..63
        int kcol = (idx & 3) * 8;
        half8 v = *(const half8*)(shw + tl * 40 + kcol);
        *(half8*)(xblk + ((size_t)tl * N_ + n) * GH_ + kcol) = v;
    }
}

// ---------- fallback: 32-t gather (round-13 exact, 1 wave/block) ----------
__global__ __launch_bounds__(64)
void k_gather32(const int* __restrict__ row_ptr, const int2* __restrict__ erec,
                const float* __restrict__ selfn,
                const half_t* __restrict__ aTh,   // [N][64] f16
                const half_t* __restrict__ ch,    // [N][32] f16 (b0 folded)
                const float* __restrict__ w0,     // row 0 used
                const half_t* __restrict__ w1B,   // swizzled w1 frags
                const float* __restrict__ b1,
                half_t* __restrict__ xblk,        // [32][N][32] f16
                int h) {
    __shared__ half_t shw[32 * 40];
    int n = blockIdx.x;
    int l = threadIdx.x;
    int tg4 = (l >> 3) * 4;
    int kc = (l & 7) * 4;
    float w0r[4];
#pragma unroll
    for (int i = 0; i < 4; ++i) w0r[i] = w0[kc + i];
    const half_t* aBase = aTh + h * 32 + tg4;
    float acc[4][4];

    auto edge_acc = [&](half4 aa, half4 cc, float nmv) {
#pragma unroll
        for (int tt = 0; tt < 4; ++tt)
#pragma unroll
            for (int i = 0; i < 4; ++i) {
                float hv = fmaxf(fmaf((float)aa[tt], w0r[i], (float)cc[i]), 0.0f);
                acc[tt][i] = fmaf(nmv, hv, acc[tt][i]);
            }
    };

    {
        float sn = selfn[n];
        half4 a4 = *(const half4*)(aBase + (size_t)n * 64);
        half4 c4 = *(const half4*)(ch + (size_t)n * GH_ + kc);
#pragma unroll
        for (int tt = 0; tt < 4; ++tt)
#pragma unroll
            for (int i = 0; i < 4; ++i) {
                float hv = fmaxf(fmaf((float)a4[tt], w0r[i], (float)c4[i]), 0.0f);
                acc[tt][i] = sn * hv;
            }
    }

    int e0 = row_ptr[n], e1 = row_ptr[n + 1];
    int e = e0;
    if (e < e1 && (e & 1)) {
        int2 r = erec[e];
        half4 a4 = *(const half4*)(aBase + (size_t)r.x * 64);
        half4 c4 = *(const half4*)(ch + (size_t)r.x * GH_ + kc);
        edge_acc(a4, c4, __int_as_float(r.y));
        ++e;
    }
    for (; e + 4 <= e1; e += 4) {
        i32x4 p0 = *(const i32x4*)(erec + e);
        i32x4 p1 = *(const i32x4*)(erec + e + 2);
        size_t s0 = (size_t)p0[0], s1 = (size_t)p0[2];
        size_t s2 = (size_t)p1[0], s3 = (size_t)p1[2];
        half4 a40 = *(const half4*)(aBase + s0 * 64);
        half4 a41 = *(const half4*)(aBase + s1 * 64);
        half4 a42 = *(const half4*)(aBase + s2 * 64);
        half4 a43 = *(const half4*)(aBase + s3 * 64);
        half4 c40 = *(const half4*)(ch + s0 * GH_ + kc);
        half4 c41 = *(const half4*)(ch + s1 * GH_ + kc);
        half4 c42 = *(const half4*)(ch + s2 * GH_ + kc);
        half4 c43 = *(const half4*)(ch + s3 * GH_ + kc);
        edge_acc(a40, c40, __int_as_float(p0[1]));
        edge_acc(a41, c41, __int_as_float(p0[3]));
        edge_acc(a42, c42, __int_as_float(p1[1]));
        edge_acc(a43, c43, __int_as_float(p1[3]));
    }
    for (; e < e1; ++e) {
        int2 r = erec[e];
        half4 a4 = *(const half4*)(aBase + (size_t)r.x * 64);
        half4 c4 = *(const half4*)(ch + (size_t)r.x * GH_ + kc);
        edge_acc(a4, c4, __int_as_float(r.y));
    }

#pragma unroll
    for (int tt = 0; tt < 4; ++tt) {
        half4 o;
#pragma unroll
        for (int i = 0; i < 4; ++i) o[i] = (half_t)acc[tt][i];
        *(half4*)(shw + (tg4 + tt) * 40 + kc) = o;
    }

    int c16 = l & 15, q = l >> 4;
    const half8* wB8 = (const half8*)w1B;
    half8 bf0 = wB8[(0 * 4 + q) * 16 + c16];
    half8 bf1 = wB8[(1 * 4 + q) * 16 + c16];
    float b1v0 = b1[c16], b1v1 = b1[16 + c16];

    const f32x4 zero = {0.0f, 0.0f, 0.0f, 0.0f};
    half8 A0 = *(const half8*)(shw + (0 * 16 + c16) * 40 + q * 8);
    half8 A1 = *(const half8*)(shw + (1 * 16 + c16) * 40 + q * 8);
    f32x4 C00 = __builtin_amdgcn_mfma_f32_16x16x32_f16(A0, bf0, zero, 0, 0, 0);
    f32x4 C01 = __builtin_amdgcn_mfma_f32_16x16x32_f16(A0, bf1, zero, 0, 0, 0);
    f32x4 C10 = __builtin_amdgcn_mfma_f32_16x16x32_f16(A1, bf0, zero, 0, 0, 0);
    f32x4 C11 = __builtin_amdgcn_mfma_f32_16x16x32_f16(A1, bf1, zero, 0, 0, 0);
#pragma unroll
    for (int reg = 0; reg < 4; ++reg) {
        shw[(q * 4 + reg) * 40 + c16]           = (half_t)fmaxf(C00[reg] + b1v0, 0.0f);
        shw[(q * 4 + reg) * 40 + 16 + c16]      = (half_t)fmaxf(C01[reg] + b1v1, 0.0f);
        shw[(16 + q * 4 + reg) * 40 + c16]      = (half_t)fmaxf(C10[reg] + b1v0, 0.0f);
        shw[(16 + q * 4 + reg) * 40 + 16 + c16] = (half_t)fmaxf(C11[reg] + b1v1, 0.0f);
    }
#pragma unroll
    for (int i = 0; i < 2; ++i) {
        int idx = i * 64 + l;
        int tl = idx >> 2;
        int kcol = (idx & 3) * 8;
        half8 v = *(const half8*)(shw + tl * 40 + kcol);
        *(half8*)(xblk + ((size_t)tl * N_ + n) * GH_ + kcol) = v;
    }
}

// ---------- MFMA GRU (one merged pass of 32 timesteps) ----------
#define HSTR_ 72
__global__ __launch_bounds__(256, 2)
void k_gru32(const half_t* __restrict__ xblk,  // [32][N][32] f16 (slice base)
             const half_t* __restrict__ wB,    // swizzled fragments
             const float* __restrict__ bih, const float* __restrict__ bhh,
             half_t* __restrict__ hA) {        // [Npad][64] f16
    __shared__ half_t hL[64 * HSTR_];
    int tid = threadIdx.x;
    int nb0 = blockIdx.x * 64;
    for (int i = tid; i < 64 * 8; i += 256) {
        int node = i >> 3, ch = i & 7;
        half8 v = *(const half8*)(hA + (size_t)(nb0 + node) * RH_ + ch * 8);
        *(half8*)(hL + node * HSTR_ + ch * 8) = v;
    }
    __syncthreads();
    int lane = tid & 63;
    int wv = tid >> 6;
    int c16 = lane & 15, q = lane >> 4;
    const half8* wB8 = (const half8*)wB;
    half8 bfr[3][12];
#pragma unroll
    for (int c = 0; c < 3; ++c)
#pragma unroll
        for (int nt = 0; nt < 12; ++nt)
            bfr[c][nt] = wB8[((c * 12 + nt) * 4 + q) * 16 + c16];
    float br[4], bz[4], bnx[4], bnh[4];
#pragma unroll
    for (int jt = 0; jt < 4; ++jt) {
        int j = jt * 16 + c16;
        br[jt]  = bih[j] + bhh[j];
        bz[jt]  = bih[64 + j] + bhh[64 + j];
        bnx[jt] = bih[128 + j];
        bnh[jt] = bhh[128 + j];
    }
    int mrow = wv * 16 + c16;
    const half_t* hrow = hL + mrow * HSTR_;
    const f32x4 zero = {0.0f, 0.0f, 0.0f, 0.0f};
#pragma unroll 1
    for (int u = 0; u < TB32_; ++u) {
        half8 ax = __builtin_nontemporal_load(
            (const half8*)(xblk + ((size_t)u * N_ + nb0 + mrow) * GH_ + q * 8));
        half8 ah0 = *(const half8*)(hrow + q * 8);
        half8 ah1 = *(const half8*)(hrow + 32 + q * 8);
        f32x4 Crz[8], Cnx[4], Cnh[4];
#pragma unroll
        for (int nt = 0; nt < 8; ++nt) {
            Crz[nt] = __builtin_amdgcn_mfma_f32_16x16x32_f16(ax,  bfr[0][nt], zero,     0, 0, 0);
            Crz[nt] = __builtin_amdgcn_mfma_f32_16x16x32_f16(ah0, bfr[1][nt], Crz[nt], 0, 0, 0);
            Crz[nt] = __builtin_amdgcn_mfma_f32_16x16x32_f16(ah1, bfr[2][nt], Crz[nt], 0, 0, 0);
        }
#pragma unroll
        for (int nt = 0; nt < 4; ++nt) {
            Cnx[nt] = __builtin_amdgcn_mfma_f32_16x16x32_f16(ax,  bfr[0][8 + nt], zero,     0, 0, 0);
            Cnh[nt] = __builtin_amdgcn_mfma_f32_16x16x32_f16(ah0, bfr[1][8 + nt], zero,     0, 0, 0);
            Cnh[nt] = __builtin_amdgcn_mfma_f32_16x16x32_f16(ah1, bfr[2][8 + nt], Cnh[nt], 0, 0, 0);
        }
#pragma unroll
        for (int jt = 0; jt < 4; ++jt) {
#pragma unroll
            for (int reg = 0; reg < 4; ++reg) {
                int nl = wv * 16 + q * 4 + reg;
                int jj = jt * 16 + c16;
                float hold = (float)hL[nl * HSTR_ + jj];
                float r  = fast_sigmoid(Crz[jt][reg] + br[jt]);
                float z  = fast_sigmoid(Crz[4 + jt][reg] + bz[jt]);
                float cd = fast_tanh(Cnx[jt][reg] + bnx[jt] + r * (Cnh[jt][reg] + bnh[jt]));
                hL[nl * HSTR_ + jj] = (half_t)((1.0f - z) * cd + z * hold);
            }
        }
    }
    __syncthreads();
    for (int i = tid; i < 64 * 8; i += 256) {
        int node = i >> 3, ch = i & 7;
        half8 v = *(const half8*)(hL + node * HSTR_ + ch * 8);
        *(half8*)(hA + (size_t)(nb0 + node) * RH_ + ch * 8) = v;
    }
}

__global__ __launch_bounds__(256)
void k_mlp(const half_t* __restrict__ hA, const float* __restrict__ w1,
           const float* __restrict__ b1, const float* __restrict__ w2,
           const float* __restrict__ b2, float* __restrict__ out) {
    int n = blockIdx.x * blockDim.x + threadIdx.x;
    if (n >= N_) return;
    float h[RH_];
    const half8* h8 = (const half8*)(hA + (size_t)n * RH_);
#pragma unroll
    for (int c = 0; c < 8; ++c) {
        half8 v = h8[c];
#pragma unroll
        for (int i = 0; i < 8; ++i) h[c * 8 + i] = (float)v[i];
    }
    float acc = b2[0];
#pragma unroll 1
    for (int j = 0; j < RH_; ++j) {
        float v = b1[j];
#pragma unroll
        for (int k = 0; k < RH_; ++k) v += w1[j * RH_ + k] * h[k];
        v = v > 0.0f ? v : 0.0f;
        acc += w2[j] * v;
    }
    out[n] = acc;
}

extern "C" void kernel_launch(void* const* d_in, const int* in_sizes, int n_in,
                              void* d_out, int out_size, void* d_ws, size_t ws_size,
                              hipStream_t stream) {
    const float* dyn     = (const float*)d_in[0];
    const float* statics = (const float*)d_in[1];
    const int*   ei      = (const int*)d_in[2];
    const float* w0      = (const float*)d_in[3];
    const float* b0      = (const float*)d_in[4];
    const float* w1      = (const float*)d_in[5];
    const float* b1      = (const float*)d_in[6];
    const float* wih     = (const float*)d_in[7];
    const float* whh     = (const float*)d_in[8];
    const float* bih     = (const float*)d_in[9];
    const float* bhh     = (const float*)d_in[10];
    const float* mw1     = (const float*)d_in[11];
    const float* mb1     = (const float*)d_in[12];
    const float* mw2     = (const float*)d_in[13];
    const float* mb2     = (const float*)d_in[14];
    const int* src = ei;
    const int* dst = ei + E_;

    char* ws = (char*)d_ws;
    auto alloc = [&](size_t elems) {        // 4B units, 256B-aligned
        elems = (elems + 63) & ~(size_t)63;
        void* p = ws; ws += elems * 4; return p;
    };
    const int NPAD = N_ + 64;
    int*    deg     = (int*)alloc(N_);
    int*    row_ptr = (int*)alloc(N_ + 4);
    int*    bsum    = (int*)alloc(256);
    int*    cnt     = (int*)alloc((size_t)N_ * 16);
    int*    rp2     = (int*)alloc((size_t)N_ * 16);
    int2*   erec    = (int2*)alloc((size_t)E_ * 2);
    float*  dinv    = (float*)alloc(N_);
    float*  selfn   = (float*)alloc(N_);
    half_t* h0s     = (half_t*)alloc((size_t)N_ * GH_ / 2);        // f16 [N,32]
    half_t* ch      = (half_t*)alloc((size_t)N_ * GH_ / 2);        // f16 [N,32]
    half_t* aTh     = (half_t*)alloc((size_t)N_ * 64 / 2);         // f16 [N,64]
    half_t* hA      = (half_t*)alloc((size_t)NPAD * RH_ / 2);      // f16 [Npad][64]
    half_t* dynT    = (half_t*)alloc((size_t)N_ * 64 / 2);         // f16 [N][64]
    half_t* wB      = (half_t*)alloc(96 * 192 / 2);
    half_t* w1B     = (half_t*)alloc(1024 / 2);
    // xblk last: [64][N][32] if workspace permits, else [32][N][32] (fallback)
    size_t used = (size_t)(ws - (char*)d_ws);
    size_t xblk64_bytes = ((size_t)64 * N_ + 64) * GH_ * sizeof(half_t);
    bool use64 = (ws_size >= used + xblk64_bytes + 4096);
    half_t* xblk = (half_t*)ws;

    auto cdiv = [](long long x, int b) { return (unsigned)((x + b - 1) / b); };
    const int B = 256;

    hipMemsetAsync(cnt, 0, (size_t)N_ * 16 * sizeof(int), stream);
    hipMemsetAsync(hA, 0, (size_t)NPAD * RH_ * sizeof(half_t), stream);

    k_transpose<<<cdiv(N_, 64), dim3(64, 4), 0, stream>>>(dyn, dynT);
    k_hist<<<cdiv(E_, B), B, 0, stream>>>(src, dst, cnt);
    k_scanA<<<NB_, B, 0, stream>>>(cnt, deg, row_ptr, bsum);
    k_scanB<<<1, B, 0, stream>>>(bsum, NB_);
    k_scanC<<<NB_, B, 0, stream>>>(row_ptr, bsum);
    k_rowscan<<<NB_, B, 0, stream>>>(row_ptr, cnt, rp2);
    k_node_init<<<NB_, B, 0, stream>>>(deg, statics, w0, dinv, selfn, h0s);
    k_scatter2<<<cdiv(E_, B), B, 0, stream>>>(src, dst, dinv, rp2, cnt, erec);
    k_wB<<<cdiv(96 * 192, B), B, 0, stream>>>(wih, whh, wB);
    k_w1B<<<4, B, 0, stream>>>(w1, w1B);
    k_aux<<<AB_ + GB_, B, 0, stream>>>(row_ptr, erec, selfn, dynT, aTh, h0s, b0, ch);

    if (use64) {
        k_gather64<<<N_, 64, 0, stream>>>(row_ptr, erec, selfn, aTh, ch, w0,
                                          w1B, b1, xblk);
        k_gru32<<<GB_, B, 0, stream>>>(xblk, wB, bih, bhh, hA);
        k_gru32<<<GB_, B, 0, stream>>>(xblk + (size_t)32 * N_ * GH_, wB, bih, bhh, hA);
    } else {
        for (int h = 0; h < 2; ++h) {
            k_gather32<<<N_, 64, 0, stream>>>(row_ptr, erec, selfn, aTh, ch, w0,
                                              w1B, b1, xblk, h);
            k_gru32<<<GB_, B, 0, stream>>>(xblk, wB, bih, bhh, hA);
        }
    }
    k_mlp<<<NB_, B, 0, stream>>>(hA, mw1, mb1, mw2, mb2, (float*)d_out);
}

// Round 15
// 892.233 us; speedup vs baseline: 1.0527x; 1.0251x over previous
//
#include <hip/hip_runtime.h>
#include <hip/hip_bf16.h>

#define T_   64
#define N_   50000
#define E_   1600000
#define GH_  32
#define RH_  64
#define TB32_ 32                   // timesteps per GRU pass (fallback)
#define GB_  782                   // gru blocks: cdiv(N,64)
#define NB_  196                   // node blocks: cdiv(N,256)
#define AB_  12500                 // aall blocks: N / (4 waves/block)

typedef _Float16 half_t;
typedef __attribute__((ext_vector_type(8))) _Float16 half8;
typedef __attribute__((ext_vector_type(4))) _Float16 half4;
typedef __attribute__((ext_vector_type(4))) float f32x4;
typedef __attribute__((ext_vector_type(4))) int i32x4;

static __device__ __forceinline__ float fast_sigmoid(float v) {
    float e = __expf(-v);
    return __builtin_amdgcn_rcpf(1.0f + e);
}
static __device__ __forceinline__ float fast_tanh(float v) {
    return 2.0f * fast_sigmoid(2.0f * v) - 1.0f;
}

// ---------- prologue ----------

// dyn [T,N] fp32 -> dynT [N,T] fp16
__global__ __launch_bounds__(256)
void k_transpose(const float* __restrict__ dyn, half_t* __restrict__ dynT) {
    __shared__ float tile[64][65];
    int n0 = blockIdx.x * 64;
    int tx = threadIdx.x, ty = threadIdx.y;
#pragma unroll
    for (int r = 0; r < 16; ++r) {
        int t = r * 4 + ty;
        int n = n0 + tx;
        tile[t][tx] = (n < N_) ? dyn[(size_t)t * N_ + n] : 0.0f;
    }
    __syncthreads();
#pragma unroll
    for (int r = 0; r < 16; ++r) {
        int nl = r * 4 + ty;
        int n = n0 + nl;
        if (n < N_) dynT[(size_t)n * 64 + tx] = (half_t)tile[tx][nl];
    }
}

// per-(dst, src-tile) histogram
__global__ void k_hist(const int* __restrict__ src, const int* __restrict__ dst,
                       int* __restrict__ cnt) {
    int e = blockIdx.x * blockDim.x + threadIdx.x;
    if (e >= E_) return;
    atomicAdd(&cnt[dst[e] * 16 + (src[e] >> 12)], 1);
}

// deg from cnt + per-block inclusive scan
__global__ __launch_bounds__(256)
void k_scanA(const int* __restrict__ cnt, int* __restrict__ deg,
             int* __restrict__ row_ptr, int* __restrict__ bsum) {
    __shared__ int buf[256];
    int tid = threadIdx.x;
    int i = blockIdx.x * 256 + tid;
    int v = 0;
    if (i < N_) {
        const int4* c4 = (const int4*)(cnt + i * 16);
#pragma unroll
        for (int c = 0; c < 4; ++c) {
            int4 w = c4[c];
            v += w.x + w.y + w.z + w.w;
        }
        deg[i] = v;
    }
    buf[tid] = v;
    __syncthreads();
#pragma unroll
    for (int off = 1; off < 256; off <<= 1) {
        int t = (tid >= off) ? buf[tid - off] : 0;
        __syncthreads();
        buf[tid] += t;
        __syncthreads();
    }
    if (i < N_) row_ptr[i + 1] = buf[tid];
    if (tid == 255) bsum[blockIdx.x] = buf[255];
}
__global__ __launch_bounds__(256)
void k_scanB(int* __restrict__ bsum, int nb) {
    __shared__ int buf[256];
    int tid = threadIdx.x;
    buf[tid] = (tid < nb) ? bsum[tid] : 0;
    __syncthreads();
#pragma unroll
    for (int off = 1; off < 256; off <<= 1) {
        int t = (tid >= off) ? buf[tid - off] : 0;
        __syncthreads();
        buf[tid] += t;
        __syncthreads();
    }
    if (tid < nb) bsum[tid] = (tid > 0) ? buf[tid - 1] : 0;
}
__global__ __launch_bounds__(256)
void k_scanC(int* __restrict__ row_ptr, const int* __restrict__ bsum) {
    int i = blockIdx.x * 256 + threadIdx.x;
    if (i == 0) row_ptr[0] = 0;
    if (i < N_) row_ptr[i + 1] += bsum[blockIdx.x];
}

// rp2[n][t] = row_ptr[n] + prefix(cnt[n][0..t)); zero cnt (reused as cursor)
__global__ __launch_bounds__(256)
void k_rowscan(const int* __restrict__ row_ptr, int* __restrict__ cnt,
               int* __restrict__ rp2) {
    int n = blockIdx.x * 256 + threadIdx.x;
    if (n >= N_) return;
    int run = row_ptr[n];
#pragma unroll
    for (int t = 0; t < 16; ++t) {
        int c = cnt[n * 16 + t];
        rp2[n * 16 + t] = run;
        run += c;
        cnt[n * 16 + t] = 0;
    }
}

__global__ __launch_bounds__(256)
void k_node_init(const int* __restrict__ deg,
                 const float* __restrict__ statics,
                 const float* __restrict__ w0,
                 float* __restrict__ dinv,
                 float* __restrict__ selfn,
                 half_t* __restrict__ h0s) {          // [N,32] f16
    int n = blockIdx.x * blockDim.x + threadIdx.x;
    if (n >= N_) return;
    float d  = (float)deg[n] + 1.0f;
    float di = rsqrtf(d);
    dinv[n] = di;
    selfn[n] = di * di;
    float s[6];
#pragma unroll
    for (int j = 0; j < 6; ++j) s[j] = statics[n * 6 + j];
    half8 o[4];
#pragma unroll
    for (int k = 0; k < GH_; ++k) {
        float v = 0.0f;
#pragma unroll
        for (int j = 0; j < 6; ++j) v += s[j] * w0[(1 + j) * GH_ + k];
        o[k >> 3][k & 7] = (half_t)v;
    }
    half8* dst8 = (half8*)(h0s + (size_t)n * GH_);
#pragma unroll
    for (int c = 0; c < 4; ++c) dst8[c] = o[c];
}

// tile-ordered scatter: 8-byte record {src, norm}
__global__ void k_scatter2(const int* __restrict__ src, const int* __restrict__ dst,
                           const float* __restrict__ dinv,
                           const int* __restrict__ rp2, int* __restrict__ cnt,
                           int2* __restrict__ erec) {
    int e = blockIdx.x * blockDim.x + threadIdx.x;
    if (e >= E_) return;
    int s = src[e], d = dst[e];
    int slot = d * 16 + (s >> 12);
    int pos = rp2[slot] + atomicAdd(&cnt[slot], 1);
    erec[pos] = make_int2(s, __float_as_int(dinv[s] * dinv[d]));
}

// pre-swizzled GRU weight fragments, f16.
__global__ void k_wB(const float* __restrict__ wih, const float* __restrict__ whh,
                     half_t* __restrict__ wB) {
    int idx = blockIdx.x * 256 + threadIdx.x;
    if (idx >= 96 * 192) return;
    int j = idx & 7;
    int r = idx >> 3;
    int m = r & 15; r >>= 4;
    int q = r & 3;  r >>= 2;
    int nt = r % 12;
    int c = r / 12;
    int k = c * 32 + q * 8 + j;
    int col = nt * 16 + m;
    float v = (k < 32) ? wih[col * 32 + k] : whh[col * 64 + (k - 32)];
    wB[idx] = (half_t)v;
}

// pre-swizzled w1 fragments, f16: w1B[((nt*4+q)*16+m)*8+j] = w1[k=q*8+j][col=nt*16+m]
__global__ void k_w1B(const float* __restrict__ w1, half_t* __restrict__ w1B) {
    int idx = blockIdx.x * 256 + threadIdx.x;
    if (idx >= 1024) return;
    int j = idx & 7;
    int m = (idx >> 3) & 15;
    int q = (idx >> 7) & 3;
    int nt = idx >> 9;
    w1B[idx] = (half_t)w1[(q * 8 + j) * GH_ + nt * 16 + m];
}

// ---------- fused aall + csagg gather (layer-1 aggregation) ----------

// aTh[n][t] f16 = agg of dyn (scalar per t).
static __device__ __forceinline__
void aall_body(int bid, const int* __restrict__ row_ptr, const int2* __restrict__ erec,
               const float* __restrict__ selfn, const half_t* __restrict__ dynT,
               half_t* __restrict__ aTh) {
    int wv = __builtin_amdgcn_readfirstlane(threadIdx.x >> 6);
    int n = bid * 4 + wv;                         // exact: AB_*4 == N_
    int lane = threadIdx.x & 63;
    float acc = selfn[n] * (float)dynT[(size_t)n * 64 + lane];
    int e0 = row_ptr[n], e1 = row_ptr[n + 1];     // wave-uniform (s_load)
    int e = e0;
    for (; e < e1 && (e & 3); ++e) {
        int2 r = erec[e];
        acc += __int_as_float(r.y) * (float)dynT[(size_t)r.x * 64 + lane];
    }
    for (; e + 4 <= e1; e += 4) {
        int4 p0 = *(const int4*)(erec + e);
        int4 p1 = *(const int4*)(erec + e + 2);
        float v0 = (float)dynT[(size_t)p0.x * 64 + lane];
        float v1 = (float)dynT[(size_t)p0.z * 64 + lane];
        float v2 = (float)dynT[(size_t)p1.x * 64 + lane];
        float v3 = (float)dynT[(size_t)p1.z * 64 + lane];
        acc += __int_as_float(p0.y) * v0 + __int_as_float(p0.w) * v1
             + __int_as_float(p1.y) * v2 + __int_as_float(p1.w) * v3;
    }
    for (; e < e1; ++e) {
        int2 r = erec[e];
        acc += __int_as_float(r.y) * (float)dynT[(size_t)r.x * 64 + lane];
    }
    aTh[(size_t)n * 64 + lane] = (half_t)acc;
}

// ch[n][32] f16 = agg of static-part (h0s) + b0 folded
static __device__ __forceinline__
void g16s_body(int bid, const int* __restrict__ row_ptr, const int2* __restrict__ erec,
               const float* __restrict__ selfn, const half_t* __restrict__ h0s,
               const float* __restrict__ b0, half_t* __restrict__ ch) {
    int gid = bid * 256 + threadIdx.x;
    int n = gid >> 2, q = gid & 3;
    if (n >= N_) return;
    const half8* f8 = (const half8*)h0s;
    float acc[8];
    {
        half8 sv = f8[(size_t)n * 4 + q];
        float sn = selfn[n];
#pragma unroll
        for (int i = 0; i < 8; ++i) acc[i] = sn * (float)sv[i];
    }
    int e0 = row_ptr[n], e1 = row_ptr[n + 1];
    int e = e0;
    for (; e < e1 && (e & 3); ++e) {
        int2 r = erec[e];
        float nm = __int_as_float(r.y);
        half8 v = f8[(size_t)r.x * 4 + q];
#pragma unroll
        for (int i = 0; i < 8; ++i) acc[i] += nm * (float)v[i];
    }
    for (; e + 4 <= e1; e += 4) {
        int4 p0 = *(const int4*)(erec + e);
        int4 p1 = *(const int4*)(erec + e + 2);
        half8 v0 = f8[(size_t)p0.x * 4 + q];
        half8 v1 = f8[(size_t)p0.z * 4 + q];
        half8 v2 = f8[(size_t)p1.x * 4 + q];
        half8 v3 = f8[(size_t)p1.z * 4 + q];
        float n0 = __int_as_float(p0.y), n1 = __int_as_float(p0.w);
        float n2 = __int_as_float(p1.y), n3 = __int_as_float(p1.w);
#pragma unroll
        for (int i = 0; i < 8; ++i)
            acc[i] += n0 * (float)v0[i] + n1 * (float)v1[i]
                    + n2 * (float)v2[i] + n3 * (float)v3[i];
    }
    for (; e < e1; ++e) {
        int2 r = erec[e];
        float nm = __int_as_float(r.y);
        half8 v = f8[(size_t)r.x * 4 + q];
#pragma unroll
        for (int i = 0; i < 8; ++i) acc[i] += nm * (float)v[i];
    }
    half8 o;
#pragma unroll
    for (int i = 0; i < 8; ++i) o[i] = (half_t)(acc[i] + b0[q * 8 + i]);
    *(half8*)(ch + (size_t)n * GH_ + q * 8) = o;
}

__global__ __launch_bounds__(256)
void k_aux(const int* __restrict__ row_ptr, const int2* __restrict__ erec,
           const float* __restrict__ selfn, const half_t* __restrict__ dynT,
           half_t* __restrict__ aTh, const half_t* __restrict__ h0s,
           const float* __restrict__ b0, half_t* __restrict__ ch) {
    if ((int)blockIdx.x < AB_)
        aall_body(blockIdx.x, row_ptr, erec, selfn, dynT, aTh);
    else
        g16s_body((int)blockIdx.x - AB_, row_ptr, erec, selfn, h0s, b0, ch);
}

// ---------- fused layer-2 gather + @w1 MFMA epilogue (ALL 64 t, one pass) ----
__global__ __launch_bounds__(64)
void k_gather64(const int* __restrict__ row_ptr, const int2* __restrict__ erec,
                const float* __restrict__ selfn,
                const half_t* __restrict__ aTh,   // [N][64] f16
                const half_t* __restrict__ ch,    // [N][32] f16 (b0 folded)
                const float* __restrict__ w0,     // row 0 used
                const half_t* __restrict__ w1B,   // swizzled w1 frags
                const float* __restrict__ b1,
                half_t* __restrict__ xblk) {      // [64][N][32] f16
    __shared__ half_t shw[64 * 40];               // one wave x 64 t x pad-40
    int n = blockIdx.x;                           // grid = N_, SGPR-uniform
    int l = threadIdx.x;                          // 0..63
    int tg8 = (l >> 3) * 8;                       // t base: 0,8,..,56
    int kc = (l & 7) * 4;                         // k chunk of 4
    float w0r[4];
#pragma unroll
    for (int i = 0; i < 4; ++i) w0r[i] = w0[kc + i];

    const half_t* aBase = aTh + tg8;              // + s*64 per src
    float acc[8][4];

    auto edge_acc = [&](half8 aa, half4 cc, float nmv) {
#pragma unroll
        for (int tt = 0; tt < 8; ++tt) {
#pragma unroll
            for (int i = 0; i < 4; ++i) {
                // fmaf(fpext(f16), f32, fpext(f16)) -> v_fma_mix_f32
                float hv = fmaxf(fmaf((float)aa[tt], w0r[i], (float)cc[i]), 0.0f);
                acc[tt][i] = fmaf(nmv, hv, acc[tt][i]);
            }
        }
    };

    {   // self-loop term
        float sn = selfn[n];
        half8 a8 = *(const half8*)(aBase + (size_t)n * 64);
        half4 c4 = *(const half4*)(ch + (size_t)n * GH_ + kc);
#pragma unroll
        for (int tt = 0; tt < 8; ++tt) {
#pragma unroll
            for (int i = 0; i < 4; ++i) {
                float hv = fmaxf(fmaf((float)a8[tt], w0r[i], (float)c4[i]), 0.0f);
                acc[tt][i] = sn * hv;
            }
        }
    }

    int e0 = row_ptr[n], e1 = row_ptr[n + 1];     // wave-uniform (s_load)
    int e = e0;
    if (e < e1 && (e & 1)) {                      // align to 16B erec pairs
        int2 r = erec[e];
        half8 a8 = *(const half8*)(aBase + (size_t)r.x * 64);
        half4 c4 = *(const half4*)(ch + (size_t)r.x * GH_ + kc);
        edge_acc(a8, c4, __int_as_float(r.y));
        ++e;
    }
    for (; e + 2 <= e1; e += 2) {
        i32x4 p0 = *(const i32x4*)(erec + e);
        size_t s0 = (size_t)p0[0], s1 = (size_t)p0[2];
        half8 a80 = *(const half8*)(aBase + s0 * 64);
        half8 a81 = *(const half8*)(aBase + s1 * 64);
        half4 c40 = *(const half4*)(ch + s0 * GH_ + kc);
        half4 c41 = *(const half4*)(ch + s1 * GH_ + kc);
        edge_acc(a80, c40, __int_as_float(p0[1]));
        edge_acc(a81, c41, __int_as_float(p0[3]));
    }
    for (; e < e1; ++e) {
        int2 r = erec[e];
        half8 a8 = *(const half8*)(aBase + (size_t)r.x * 64);
        half4 c4 = *(const half4*)(ch + (size_t)r.x * GH_ + kc);
        edge_acc(a8, c4, __int_as_float(r.y));
    }

    // acc -> wave-private LDS tile (f16); pad-40 rows keep half8 reads aligned.
#pragma unroll
    for (int tt = 0; tt < 8; ++tt) {
        half4 o;
#pragma unroll
        for (int i = 0; i < 4; ++i) o[i] = (half_t)acc[tt][i];
        *(half4*)(shw + (tg8 + tt) * 40 + kc) = o;
    }

    // epilogue operands (loaded after the edge loop)
    int c16 = l & 15, q = l >> 4;
    const half8* wB8 = (const half8*)w1B;
    half8 bf0 = wB8[(0 * 4 + q) * 16 + c16];
    half8 bf1 = wB8[(1 * 4 + q) * 16 + c16];
    float b1v0 = b1[c16], b1v1 = b1[16 + c16];

    const f32x4 zero = {0.0f, 0.0f, 0.0f, 0.0f};
    half8 A[4];
#pragma unroll
    for (int b = 0; b < 4; ++b)
        A[b] = *(const half8*)(shw + (b * 16 + c16) * 40 + q * 8);
    f32x4 C0[4], C1[4];
#pragma unroll
    for (int b = 0; b < 4; ++b) {
        C0[b] = __builtin_amdgcn_mfma_f32_16x16x32_f16(A[b], bf0, zero, 0, 0, 0);
        C1[b] = __builtin_amdgcn_mfma_f32_16x16x32_f16(A[b], bf1, zero, 0, 0, 0);
    }
    // writeback (A[] already in regs, safe to clobber rows)
#pragma unroll
    for (int b = 0; b < 4; ++b)
#pragma unroll
        for (int reg = 0; reg < 4; ++reg) {
            int row = b * 16 + q * 4 + reg;
            shw[row * 40 + c16]      = (half_t)fmaxf(C0[b][reg] + b1v0, 0.0f);
            shw[row * 40 + 16 + c16] = (half_t)fmaxf(C1[b][reg] + b1v1, 0.0f);
        }

    // coalesced store: 4 x half8/lane; 4 lanes cover one full 64B t-row
#pragma unroll
    for (int i = 0; i < 4; ++i) {
        int idx = i * 64 + l;
        int tl = idx >> 2;                        // 0..63
        int kcol = (idx & 3) * 8;
        half8 v = *(const half8*)(shw + tl * 40 + kcol);
        *(half8*)(xblk + ((size_t)tl * N_ + n) * GH_ + kcol) = v;
    }
}

// ---------- fallback: 32-t gather (round-13 exact, 1 wave/block) ----------
__global__ __launch_bounds__(64)
void k_gather32(const int* __restrict__ row_ptr, const int2* __restrict__ erec,
                const float* __restrict__ selfn,
                const half_t* __restrict__ aTh,   // [N][64] f16
                const half_t* __restrict__ ch,    // [N][32] f16 (b0 folded)
                const float* __restrict__ w0,     // row 0 used
                const half_t* __restrict__ w1B,   // swizzled w1 frags
                const float* __restrict__ b1,
                half_t* __restrict__ xblk,        // [32][N][32] f16
                int h) {
    __shared__ half_t shw[32 * 40];
    int n = blockIdx.x;
    int l = threadIdx.x;
    int tg4 = (l >> 3) * 4;
    int kc = (l & 7) * 4;
    float w0r[4];
#pragma unroll
    for (int i = 0; i < 4; ++i) w0r[i] = w0[kc + i];
    const half_t* aBase = aTh + h * 32 + tg4;
    float acc[4][4];

    auto edge_acc = [&](half4 aa, half4 cc, float nmv) {
#pragma unroll
        for (int tt = 0; tt < 4; ++tt)
#pragma unroll
            for (int i = 0; i < 4; ++i) {
                float hv = fmaxf(fmaf((float)aa[tt], w0r[i], (float)cc[i]), 0.0f);
                acc[tt][i] = fmaf(nmv, hv, acc[tt][i]);
            }
    };

    {
        float sn = selfn[n];
        half4 a4 = *(const half4*)(aBase + (size_t)n * 64);
        half4 c4 = *(const half4*)(ch + (size_t)n * GH_ + kc);
#pragma unroll
        for (int tt = 0; tt < 4; ++tt)
#pragma unroll
            for (int i = 0; i < 4; ++i) {
                float hv = fmaxf(fmaf((float)a4[tt], w0r[i], (float)c4[i]), 0.0f);
                acc[tt][i] = sn * hv;
            }
    }

    int e0 = row_ptr[n], e1 = row_ptr[n + 1];
    int e = e0;
    if (e < e1 && (e & 1)) {
        int2 r = erec[e];
        half4 a4 = *(const half4*)(aBase + (size_t)r.x * 64);
        half4 c4 = *(const half4*)(ch + (size_t)r.x * GH_ + kc);
        edge_acc(a4, c4, __int_as_float(r.y));
        ++e;
    }
    for (; e + 4 <= e1; e += 4) {
        i32x4 p0 = *(const i32x4*)(erec + e);
        i32x4 p1 = *(const i32x4*)(erec + e + 2);
        size_t s0 = (size_t)p0[0], s1 = (size_t)p0[2];
        size_t s2 = (size_t)p1[0], s3 = (size_t)p1[2];
        half4 a40 = *(const half4*)(aBase + s0 * 64);
        half4 a41 = *(const half4*)(aBase + s1 * 64);
        half4 a42 = *(const half4*)(aBase + s2 * 64);
        half4 a43 = *(const half4*)(aBase + s3 * 64);
        half4 c40 = *(const half4*)(ch + s0 * GH_ + kc);
        half4 c41 = *(const half4*)(ch + s1 * GH_ + kc);
        half4 c42 = *(const half4*)(ch + s2 * GH_ + kc);
        half4 c43 = *(const half4*)(ch + s3 * GH_ + kc);
        edge_acc(a40, c40, __int_as_float(p0[1]));
        edge_acc(a41, c41, __int_as_float(p0[3]));
        edge_acc(a42, c42, __int_as_float(p1[1]));
        edge_acc(a43, c43, __int_as_float(p1[3]));
    }
    for (; e < e1; ++e) {
        int2 r = erec[e];
        half4 a4 = *(const half4*)(aBase + (size_t)r.x * 64);
        half4 c4 = *(const half4*)(ch + (size_t)r.x * GH_ + kc);
        edge_acc(a4, c4, __int_as_float(r.y));
    }

#pragma unroll
    for (int tt = 0; tt < 4; ++tt) {
        half4 o;
#pragma unroll
        for (int i = 0; i < 4; ++i) o[i] = (half_t)acc[tt][i];
        *(half4*)(shw + (tg4 + tt) * 40 + kc) = o;
    }

    int c16 = l & 15, q = l >> 4;
    const half8* wB8 = (const half8*)w1B;
    half8 bf0 = wB8[(0 * 4 + q) * 16 + c16];
    half8 bf1 = wB8[(1 * 4 + q) * 16 + c16];
    float b1v0 = b1[c16], b1v1 = b1[16 + c16];

    const f32x4 zero = {0.0f, 0.0f, 0.0f, 0.0f};
    half8 A0 = *(const half8*)(shw + (0 * 16 + c16) * 40 + q * 8);
    half8 A1 = *(const half8*)(shw + (1 * 16 + c16) * 40 + q * 8);
    f32x4 C00 = __builtin_amdgcn_mfma_f32_16x16x32_f16(A0, bf0, zero, 0, 0, 0);
    f32x4 C01 = __builtin_amdgcn_mfma_f32_16x16x32_f16(A0, bf1, zero, 0, 0, 0);
    f32x4 C10 = __builtin_amdgcn_mfma_f32_16x16x32_f16(A1, bf0, zero, 0, 0, 0);
    f32x4 C11 = __builtin_amdgcn_mfma_f32_16x16x32_f16(A1, bf1, zero, 0, 0, 0);
#pragma unroll
    for (int reg = 0; reg < 4; ++reg) {
        shw[(q * 4 + reg) * 40 + c16]           = (half_t)fmaxf(C00[reg] + b1v0, 0.0f);
        shw[(q * 4 + reg) * 40 + 16 + c16]      = (half_t)fmaxf(C01[reg] + b1v1, 0.0f);
        shw[(16 + q * 4 + reg) * 40 + c16]      = (half_t)fmaxf(C10[reg] + b1v0, 0.0f);
        shw[(16 + q * 4 + reg) * 40 + 16 + c16] = (half_t)fmaxf(C11[reg] + b1v1, 0.0f);
    }
#pragma unroll
    for (int i = 0; i < 2; ++i) {
        int idx = i * 64 + l;
        int tl = idx >> 2;
        int kcol = (idx & 3) * 8;
        half8 v = *(const half8*)(shw + tl * 40 + kcol);
        *(half8*)(xblk + ((size_t)tl * N_ + n) * GH_ + kcol) = v;
    }
}

#define HSTR_ 72

// ---------- merged MFMA GRU (64 timesteps) + MLP epilogue (use64 path) ----
// h0 = 0 -> zero-init hL (wave-private rows, no barrier); no hA roundtrip.
// After the u-loop, h for the block's 64 nodes sits in hL -> compute
// out = w2 . relu(w1 . h + b1) + b2 directly (j-range wave-uniform so
// mw1 rows stay s_loads, like k_mlp), reduce 4 wave-partials via LDS.
__global__ __launch_bounds__(256, 2)
void k_gru64m(const half_t* __restrict__ xblk,  // [64][N][32] f16
              const half_t* __restrict__ wB,    // swizzled fragments
              const float* __restrict__ bih, const float* __restrict__ bhh,
              const float* __restrict__ mw1, const float* __restrict__ mb1,
              const float* __restrict__ mw2, const float* __restrict__ mb2,
              float* __restrict__ out) {
    __shared__ half_t hL[64 * HSTR_];
    __shared__ float pbuf[4 * 64];
    int tid = threadIdx.x;
    int nb0 = blockIdx.x * 64;
    int lane = tid & 63;
    int wv = tid >> 6;
    {   // zero-init own wave's 16 rows (wave-private -> no barrier needed)
        int row = wv * 16 + (lane >> 2);
        int col = (lane & 3) * 16;
        half8 z = {};
        *(half8*)(hL + row * HSTR_ + col) = z;
        *(half8*)(hL + row * HSTR_ + col + 8) = z;
    }
    int c16 = lane & 15, q = lane >> 4;
    const half8* wB8 = (const half8*)wB;
    half8 bfr[3][12];
#pragma unroll
    for (int c = 0; c < 3; ++c)
#pragma unroll
        for (int nt = 0; nt < 12; ++nt)
            bfr[c][nt] = wB8[((c * 12 + nt) * 4 + q) * 16 + c16];
    float br[4], bz[4], bnx[4], bnh[4];
#pragma unroll
    for (int jt = 0; jt < 4; ++jt) {
        int j = jt * 16 + c16;
        br[jt]  = bih[j] + bhh[j];
        bz[jt]  = bih[64 + j] + bhh[64 + j];
        bnx[jt] = bih[128 + j];
        bnh[jt] = bhh[128 + j];
    }
    int mrow = wv * 16 + c16;
    const half_t* hrow = hL + mrow * HSTR_;
    const f32x4 zero = {0.0f, 0.0f, 0.0f, 0.0f};
#pragma unroll 1
    for (int u = 0; u < T_; ++u) {
        half8 ax = __builtin_nontemporal_load(
            (const half8*)(xblk + ((size_t)u * N_ + nb0 + mrow) * GH_ + q * 8));
        half8 ah0 = *(const half8*)(hrow + q * 8);
        half8 ah1 = *(const half8*)(hrow + 32 + q * 8);
        f32x4 Crz[8], Cnx[4], Cnh[4];
#pragma unroll
        for (int nt = 0; nt < 8; ++nt) {
            Crz[nt] = __builtin_amdgcn_mfma_f32_16x16x32_f16(ax,  bfr[0][nt], zero,     0, 0, 0);
            Crz[nt] = __builtin_amdgcn_mfma_f32_16x16x32_f16(ah0, bfr[1][nt], Crz[nt], 0, 0, 0);
            Crz[nt] = __builtin_amdgcn_mfma_f32_16x16x32_f16(ah1, bfr[2][nt], Crz[nt], 0, 0, 0);
        }
#pragma unroll
        for (int nt = 0; nt < 4; ++nt) {
            Cnx[nt] = __builtin_amdgcn_mfma_f32_16x16x32_f16(ax,  bfr[0][8 + nt], zero,     0, 0, 0);
            Cnh[nt] = __builtin_amdgcn_mfma_f32_16x16x32_f16(ah0, bfr[1][8 + nt], zero,     0, 0, 0);
            Cnh[nt] = __builtin_amdgcn_mfma_f32_16x16x32_f16(ah1, bfr[2][8 + nt], Cnh[nt], 0, 0, 0);
        }
#pragma unroll
        for (int jt = 0; jt < 4; ++jt) {
#pragma unroll
            for (int reg = 0; reg < 4; ++reg) {
                int nl = wv * 16 + q * 4 + reg;
                int jj = jt * 16 + c16;
                float hold = (float)hL[nl * HSTR_ + jj];
                float r  = fast_sigmoid(Crz[jt][reg] + br[jt]);
                float z  = fast_sigmoid(Crz[4 + jt][reg] + bz[jt]);
                float cd = fast_tanh(Cnx[jt][reg] + bnx[jt] + r * (Cnh[jt][reg] + bnh[jt]));
                hL[nl * HSTR_ + jj] = (half_t)((1.0f - z) * cd + z * hold);
            }
        }
    }
    __syncthreads();
    // ---- MLP epilogue: thread t -> node (t&63), j-range (t>>6)*16..+16 ----
    int nd = tid & 63;
    int jb = tid >> 6;                            // wave-uniform
    float h[RH_];
    const half8* hp = (const half8*)(hL + nd * HSTR_);
#pragma unroll
    for (int c = 0; c < 8; ++c) {
        half8 v = hp[c];
#pragma unroll
        for (int i = 0; i < 8; ++i) h[c * 8 + i] = (float)v[i];
    }
    float part = 0.0f;
#pragma unroll 1
    for (int jj = 0; jj < 16; ++jj) {
        int j = jb * 16 + jj;                     // wave-uniform -> s_loads
        float v = mb1[j];
#pragma unroll
        for (int k = 0; k < RH_; ++k) v += mw1[j * RH_ + k] * h[k];
        v = v > 0.0f ? v : 0.0f;
        part += mw2[j] * v;
    }
    pbuf[jb * 64 + nd] = part;
    __syncthreads();
    if (tid < 64) {
        int n = nb0 + tid;
        if (n < N_)
            out[n] = mb2[0] + pbuf[tid] + pbuf[64 + tid]
                   + pbuf[128 + tid] + pbuf[192 + tid];
    }
}

// ---------- fallback: MFMA GRU (32 timesteps) + separate MLP ----------
__global__ __launch_bounds__(256, 2)
void k_gru32(const half_t* __restrict__ xblk,  // [32][N][32] f16 (slice base)
             const half_t* __restrict__ wB,    // swizzled fragments
             const float* __restrict__ bih, const float* __restrict__ bhh,
             half_t* __restrict__ hA) {        // [Npad][64] f16
    __shared__ half_t hL[64 * HSTR_];
    int tid = threadIdx.x;
    int nb0 = blockIdx.x * 64;
    for (int i = tid; i < 64 * 8; i += 256) {
        int node = i >> 3, ch = i & 7;
        half8 v = *(const half8*)(hA + (size_t)(nb0 + node) * RH_ + ch * 8);
        *(half8*)(hL + node * HSTR_ + ch * 8) = v;
    }
    __syncthreads();
    int lane = tid & 63;
    int wv = tid >> 6;
    int c16 = lane & 15, q = lane >> 4;
    const half8* wB8 = (const half8*)wB;
    half8 bfr[3][12];
#pragma unroll
    for (int c = 0; c < 3; ++c)
#pragma unroll
        for (int nt = 0; nt < 12; ++nt)
            bfr[c][nt] = wB8[((c * 12 + nt) * 4 + q) * 16 + c16];
    float br[4], bz[4], bnx[4], bnh[4];
#pragma unroll
    for (int jt = 0; jt < 4; ++jt) {
        int j = jt * 16 + c16;
        br[jt]  = bih[j] + bhh[j];
        bz[jt]  = bih[64 + j] + bhh[64 + j];
        bnx[jt] = bih[128 + j];
        bnh[jt] = bhh[128 + j];
    }
    int mrow = wv * 16 + c16;
    const half_t* hrow = hL + mrow * HSTR_;
    const f32x4 zero = {0.0f, 0.0f, 0.0f, 0.0f};
#pragma unroll 1
    for (int u = 0; u < TB32_; ++u) {
        half8 ax = __builtin_nontemporal_load(
            (const half8*)(xblk + ((size_t)u * N_ + nb0 + mrow) * GH_ + q * 8));
        half8 ah0 = *(const half8*)(hrow + q * 8);
        half8 ah1 = *(const half8*)(hrow + 32 + q * 8);
        f32x4 Crz[8], Cnx[4], Cnh[4];
#pragma unroll
        for (int nt = 0; nt < 8; ++nt) {
            Crz[nt] = __builtin_amdgcn_mfma_f32_16x16x32_f16(ax,  bfr[0][nt], zero,     0, 0, 0);
            Crz[nt] = __builtin_amdgcn_mfma_f32_16x16x32_f16(ah0, bfr[1][nt], Crz[nt], 0, 0, 0);
            Crz[nt] = __builtin_amdgcn_mfma_f32_16x16x32_f16(ah1, bfr[2][nt], Crz[nt], 0, 0, 0);
        }
#pragma unroll
        for (int nt = 0; nt < 4; ++nt) {
            Cnx[nt] = __builtin_amdgcn_mfma_f32_16x16x32_f16(ax,  bfr[0][8 + nt], zero,     0, 0, 0);
            Cnh[nt] = __builtin_amdgcn_mfma_f32_16x16x32_f16(ah0, bfr[1][8 + nt], zero,     0, 0, 0);
            Cnh[nt] = __builtin_amdgcn_mfma_f32_16x16x32_f16(ah1, bfr[2][8 + nt], Cnh[nt], 0, 0, 0);
        }
#pragma unroll
        for (int jt = 0; jt < 4; ++jt) {
#pragma unroll
            for (int reg = 0; reg < 4; ++reg) {
                int nl = wv * 16 + q * 4 + reg;
                int jj = jt * 16 + c16;
                float hold = (float)hL[nl * HSTR_ + jj];
                float r  = fast_sigmoid(Crz[jt][reg] + br[jt]);
                float z  = fast_sigmoid(Crz[4 + jt][reg] + bz[jt]);
                float cd = fast_tanh(Cnx[jt][reg] + bnx[jt] + r * (Cnh[jt][reg] + bnh[jt]));
                hL[nl * HSTR_ + jj] = (half_t)((1.0f - z) * cd + z * hold);
            }
        }
    }
    __syncthreads();
    for (int i = tid; i < 64 * 8; i += 256) {
        int node = i >> 3, ch = i & 7;
        half8 v = *(const half8*)(hL + node * HSTR_ + ch * 8);
        *(half8*)(hA + (size_t)(nb0 + node) * RH_ + ch * 8) = v;
    }
}

__global__ __launch_bounds__(256)
void k_mlp(const half_t* __restrict__ hA, const float* __restrict__ w1,
           const float* __restrict__ b1, const float* __restrict__ w2,
           const float* __restrict__ b2, float* __restrict__ out) {
    int n = blockIdx.x * blockDim.x + threadIdx.x;
    if (n >= N_) return;
    float h[RH_];
    const half8* h8 = (const half8*)(hA + (size_t)n * RH_);
#pragma unroll
    for (int c = 0; c < 8; ++c) {
        half8 v = h8[c];
#pragma unroll
        for (int i = 0; i < 8; ++i) h[c * 8 + i] = (float)v[i];
    }
    float acc = b2[0];
#pragma unroll 1
    for (int j = 0; j < RH_; ++j) {
        float v = b1[j];
#pragma unroll
        for (int k = 0; k < RH_; ++k) v += w1[j * RH_ + k] * h[k];
        v = v > 0.0f ? v : 0.0f;
        acc += w2[j] * v;
    }
    out[n] = acc;
}

extern "C" void kernel_launch(void* const* d_in, const int* in_sizes, int n_in,
                              void* d_out, int out_size, void* d_ws, size_t ws_size,
                              hipStream_t stream) {
    const float* dyn     = (const float*)d_in[0];
    const float* statics = (const float*)d_in[1];
    const int*   ei      = (const int*)d_in[2];
    const float* w0      = (const float*)d_in[3];
    const float* b0      = (const float*)d_in[4];
    const float* w1      = (const float*)d_in[5];
    const float* b1      = (const float*)d_in[6];
    const float* wih     = (const float*)d_in[7];
    const float* whh     = (const float*)d_in[8];
    const float* bih     = (const float*)d_in[9];
    const float* bhh     = (const float*)d_in[10];
    const float* mw1     = (const float*)d_in[11];
    const float* mb1     = (const float*)d_in[12];
    const float* mw2     = (const float*)d_in[13];
    const float* mb2     = (const float*)d_in[14];
    const int* src = ei;
    const int* dst = ei + E_;

    char* ws = (char*)d_ws;
    auto alloc = [&](size_t elems) {        // 4B units, 256B-aligned
        elems = (elems + 63) & ~(size_t)63;
        void* p = ws; ws += elems * 4; return p;
    };
    const int NPAD = N_ + 64;
    int*    deg     = (int*)alloc(N_);
    int*    row_ptr = (int*)alloc(N_ + 4);
    int*    bsum    = (int*)alloc(256);
    int*    cnt     = (int*)alloc((size_t)N_ * 16);
    int*    rp2     = (int*)alloc((size_t)N_ * 16);
    int2*   erec    = (int2*)alloc((size_t)E_ * 2);
    float*  dinv    = (float*)alloc(N_);
    float*  selfn   = (float*)alloc(N_);
    half_t* h0s     = (half_t*)alloc((size_t)N_ * GH_ / 2);        // f16 [N,32]
    half_t* ch      = (half_t*)alloc((size_t)N_ * GH_ / 2);        // f16 [N,32]
    half_t* aTh     = (half_t*)alloc((size_t)N_ * 64 / 2);         // f16 [N,64]
    half_t* hA      = (half_t*)alloc((size_t)NPAD * RH_ / 2);      // f16 [Npad][64]
    half_t* dynT    = (half_t*)alloc((size_t)N_ * 64 / 2);         // f16 [N][64]
    half_t* wB      = (half_t*)alloc(96 * 192 / 2);
    half_t* w1B     = (half_t*)alloc(1024 / 2);
    // xblk last: [64][N][32] if workspace permits, else [32][N][32] (fallback)
    size_t used = (size_t)(ws - (char*)d_ws);
    size_t xblk64_bytes = ((size_t)64 * N_ + 64) * GH_ * sizeof(half_t);
    bool use64 = (ws_size >= used + xblk64_bytes + 4096);
    half_t* xblk = (half_t*)ws;

    auto cdiv = [](long long x, int b) { return (unsigned)((x + b - 1) / b); };
    const int B = 256;

    hipMemsetAsync(cnt, 0, (size_t)N_ * 16 * sizeof(int), stream);
    hipMemsetAsync(hA, 0, (size_t)NPAD * RH_ * sizeof(half_t), stream);

    k_transpose<<<cdiv(N_, 64), dim3(64, 4), 0, stream>>>(dyn, dynT);
    k_hist<<<cdiv(E_, B), B, 0, stream>>>(src, dst, cnt);
    k_scanA<<<NB_, B, 0, stream>>>(cnt, deg, row_ptr, bsum);
    k_scanB<<<1, B, 0, stream>>>(bsum, NB_);
    k_scanC<<<NB_, B, 0, stream>>>(row_ptr, bsum);
    k_rowscan<<<NB_, B, 0, stream>>>(row_ptr, cnt, rp2);
    k_node_init<<<NB_, B, 0, stream>>>(deg, statics, w0, dinv, selfn, h0s);
    k_scatter2<<<cdiv(E_, B), B, 0, stream>>>(src, dst, dinv, rp2, cnt, erec);
    k_wB<<<cdiv(96 * 192, B), B, 0, stream>>>(wih, whh, wB);
    k_w1B<<<4, B, 0, stream>>>(w1, w1B);
    k_aux<<<AB_ + GB_, B, 0, stream>>>(row_ptr, erec, selfn, dynT, aTh, h0s, b0, ch);

    if (use64) {
        k_gather64<<<N_, 64, 0, stream>>>(row_ptr, erec, selfn, aTh, ch, w0,
                                          w1B, b1, xblk);
        k_gru64m<<<GB_, B, 0, stream>>>(xblk, wB, bih, bhh,
                                        mw1, mb1, mw2, mb2, (float*)d_out);
    } else {
        for (int h = 0; h < 2; ++h) {
            k_gather32<<<N_, 64, 0, stream>>>(row_ptr, erec, selfn, aTh, ch, w0,
                                              w1B, b1, xblk, h);
            k_gru32<<<GB_, B, 0, stream>>>(xblk, wB, bih, bhh, hA);
        }
        k_mlp<<<NB_, B, 0, stream>>>(hA, mw1, mb1, mw2, mb2, (float*)d_out);
    }
}